// Round 10
// baseline (1562.374 us; speedup 1.0000x reference)
//
#include <hip/hip_runtime.h>
#include <hip/hip_bf16.h>

namespace {

constexpr int B_ = 2, H_ = 48, W_ = 48, DM_ = 96, DI_ = 192, NS_ = 16, RK_ = 6, K_ = 6;
constexpr int L_ = H_ * W_;
constexpr int C_ = 96;            // chunks per (b,k) stream
constexpr int LC_ = L_ / C_;      // 24 steps per chunk
constexpr int NPROJ = RK_ + 2 * NS_;  // 38
constexpr int NPAD = 48;
constexpr int GRID = 1024, NTHR = 256;
// Co-residency arithmetic (deadlock-free barrier):
//   __launch_bounds__(256,4) -> VGPR<=128 -> 4 waves/SIMD ok
//   LDS 37,504B * 4 = 150,016 <= 163,840  -> 4 blocks/CU
//   4 blocks/CU * 256 CU = 1024 = GRID    -> all blocks resident.

struct MegaP {
  const float *x, *y, *kin, *inpw, *convw, *convb, *xpw, *dtw, *dtb, *alogs, *Dsp, *lnw, *lnb, *opw;
  float *out;
  float *xv, *yv, *zg, *xs, *Bsb, *Csb, *out_y, *SHin, *Sdl, *wT, *xpwT, *wInT, *dts, *cwT;
  unsigned *bar;
};

__device__ __forceinline__ float sigmoidf_(float v) { return 1.f / (1.f + __expf(-v)); }

// softplus(dtb + dts(row)·dtw(d)) — identical in scan1 and scan3.
__device__ __forceinline__ float delta_of(const float* __restrict__ dp,
                                          const float* __restrict__ wdt, float bias) {
  float s = bias;
#pragma unroll
  for (int r = 0; r < RK_; ++r) s += dp[r] * wdt[r];
  return (s > 20.f) ? s : __logf(1.f + __expf(s));
}

// Device-scope grid barrier (generation counter). All GRID blocks co-resident.
__device__ __forceinline__ void gbar(unsigned* cnt, unsigned* gen) {
  __syncthreads();
  if (threadIdx.x == 0) {
    __threadfence();   // release: flush this XCD's L2 to device coherence point
    unsigned g = __hip_atomic_load(gen, __ATOMIC_RELAXED, __HIP_MEMORY_SCOPE_AGENT);
    if (__hip_atomic_fetch_add(cnt, 1u, __ATOMIC_ACQ_REL, __HIP_MEMORY_SCOPE_AGENT) ==
        (unsigned)GRID - 1u) {
      __hip_atomic_store(cnt, 0u, __ATOMIC_RELAXED, __HIP_MEMORY_SCOPE_AGENT);
      __hip_atomic_store(gen, g + 1u, __ATOMIC_RELEASE, __HIP_MEMORY_SCOPE_AGENT);
    } else {
      while (__hip_atomic_load(gen, __ATOMIC_ACQUIRE, __HIP_MEMORY_SCOPE_AGENT) == g)
        __builtin_amdgcn_s_sleep(2);
    }
    __threadfence();   // acquire: invalidate L1/L2 before this block reads
  }
  __syncthreads();
}

__global__ void __launch_bounds__(NTHR, 4) k_mega(MegaP p) {
  __shared__ float smem[9376];   // 37,504 B: max(P1 7232, P3 2592, P7 9376) floats
  const int tid = threadIdx.x;
  const int gtid = blockIdx.x * NTHR + tid;
  const int gsize = GRID * NTHR;
  unsigned* cnt = p.bar;
  unsigned* gen = p.bar + 32;

  // ================= P0: weight transposes =================
  for (int i = gtid; i < DM_ * 2 * DI_; i += gsize) {
    int c = i / (2 * DI_), o = i % (2 * DI_);
    p.wInT[i] = p.inpw[(size_t)o * DM_ + c];
  }
  for (int i = gtid; i < K_ * DI_ * NPAD; i += gsize) {
    int k = i / (DI_ * NPAD), r = i % (DI_ * NPAD);
    int dd = r / NPAD, c = r % NPAD;
    p.xpwT[i] = (c < NPROJ) ? p.xpw[((size_t)k * NPROJ + c) * DI_ + dd] : 0.f;
  }
  for (int i = gtid; i < DI_ * DM_; i += gsize) {
    int c = i / DM_, o = i % DM_;
    p.wT[i] = p.opw[(size_t)o * DI_ + c];
  }
  for (int i = gtid; i < 9 * DI_; i += gsize) {
    int j = i / DI_, d = i % DI_;
    p.cwT[i] = p.convw[d * 9 + j];
  }
  gbar(cnt, gen);

  // ================= P1: in_proj GEMM (432 tiles, 32 rows each) =================
  {
    float* As = smem;            // [32][33]
    float* Ws = smem + 1056;     // [32][193]
    constexpr int BPS = (B_ * L_) / 32;   // 144
    for (int tile = blockIdx.x; tile < 3 * BPS; tile += GRID) {
      int s = tile / BPS;
      int row0 = (tile % BPS) * 32;
      const float* src = (s == 0) ? p.x : (s == 1) ? p.y : p.kin;
      float* dst = (s == 0) ? p.xv : (s == 1) ? p.yv : p.zg;
      int nbase = (s == 2) ? DI_ : 0;
      int tm = tid >> 4, tn = tid & 15;
      float acc[2][12];
#pragma unroll
      for (int i = 0; i < 2; ++i)
#pragma unroll
        for (int j = 0; j < 12; ++j) acc[i][j] = 0.f;
      for (int k0 = 0; k0 < DM_; k0 += 32) {
        {
          int r = tid >> 3, c4 = (tid & 7) << 2;
          float4 v = *reinterpret_cast<const float4*>(
              &src[(size_t)(row0 + r) * DM_ + k0 + c4]);
          As[r * 33 + c4] = v.x; As[r * 33 + c4 + 1] = v.y;
          As[r * 33 + c4 + 2] = v.z; As[r * 33 + c4 + 3] = v.w;
        }
#pragma unroll
        for (int it = 0; it < 6; ++it) {
          int i = tid + it * 256;
          int r = i / 48, c4 = (i % 48) << 2;
          float4 v = *reinterpret_cast<const float4*>(
              &p.wInT[(size_t)(k0 + r) * (2 * DI_) + nbase + c4]);
          Ws[r * 193 + c4] = v.x; Ws[r * 193 + c4 + 1] = v.y;
          Ws[r * 193 + c4 + 2] = v.z; Ws[r * 193 + c4 + 3] = v.w;
        }
        __syncthreads();
#pragma unroll
        for (int kk = 0; kk < 32; ++kk) {
          float a0 = As[(tm * 2 + 0) * 33 + kk], a1 = As[(tm * 2 + 1) * 33 + kk];
          float w[12];
#pragma unroll
          for (int j = 0; j < 12; ++j) w[j] = Ws[kk * 193 + tn * 12 + j];
#pragma unroll
          for (int j = 0; j < 12; ++j) { acc[0][j] += a0 * w[j]; acc[1][j] += a1 * w[j]; }
        }
        __syncthreads();
      }
#pragma unroll
      for (int i = 0; i < 2; ++i) {
        size_t ob = (size_t)(row0 + tm * 2 + i) * DI_ + tn * 12;
#pragma unroll
        for (int j4 = 0; j4 < 3; ++j4) {
          float4 v;
          v.x = acc[i][j4 * 4 + 0]; v.y = acc[i][j4 * 4 + 1];
          v.z = acc[i][j4 * 4 + 2]; v.w = acc[i][j4 * 4 + 3];
          if (s == 2) {
            v.x *= sigmoidf_(v.x); v.y *= sigmoidf_(v.y);
            v.z *= sigmoidf_(v.z); v.w *= sigmoidf_(v.w);
          }
          *reinterpret_cast<float4*>(&dst[ob + j4 * 4]) = v;
        }
      }
    }
  }
  gbar(cnt, gen);

  // ================= P2: conv 3x3 + SiLU -> 6 direction streams =================
  for (int i = gtid; i < (B_ * L_) * 48; i += gsize) {
    int pix = i / 48, q = i % 48;
    int b = pix / L_, l = pix % L_;
    int h = l / W_, w = l % W_;
    int d4 = q << 2;
    float4 ax = *reinterpret_cast<const float4*>(&p.convb[d4]);
    float4 ay = ax;
#pragma unroll
    for (int kh = 0; kh < 3; ++kh) {
      int hh = h + kh - 1;
      if ((unsigned)hh >= (unsigned)H_) continue;
#pragma unroll
      for (int kw = 0; kw < 3; ++kw) {
        int ww = w + kw - 1;
        if ((unsigned)ww >= (unsigned)W_) continue;
        float4 wk = *reinterpret_cast<const float4*>(&p.cwT[(kh * 3 + kw) * DI_ + d4]);
        size_t idx = ((size_t)b * L_ + hh * W_ + ww) * DI_ + d4;
        float4 vx = *reinterpret_cast<const float4*>(&p.xv[idx]);
        float4 vy = *reinterpret_cast<const float4*>(&p.yv[idx]);
        ax.x += vx.x * wk.x; ax.y += vx.y * wk.y; ax.z += vx.z * wk.z; ax.w += vx.w * wk.w;
        ay.x += vy.x * wk.x; ay.y += vy.y * wk.y; ay.z += vy.z * wk.z; ay.w += vy.w * wk.w;
      }
    }
    ax.x *= sigmoidf_(ax.x); ax.y *= sigmoidf_(ax.y);
    ax.z *= sigmoidf_(ax.z); ax.w *= sigmoidf_(ax.w);
    ay.x *= sigmoidf_(ay.x); ay.y *= sigmoidf_(ay.y);
    ay.z *= sigmoidf_(ay.z); ay.w *= sigmoidf_(ay.w);
    size_t base = (size_t)b * K_ * L_;
    int lv = w * H_ + h;
    int lv2 = ((w - h + W_) % W_) * H_ + h;
    *reinterpret_cast<float4*>(&p.xs[(base + (size_t)0 * L_ + l) * DI_ + d4]) = ax;
    *reinterpret_cast<float4*>(&p.xs[(base + (size_t)3 * L_ + (L_ - 1 - l)) * DI_ + d4]) = ax;
    *reinterpret_cast<float4*>(&p.xs[(base + (size_t)1 * L_ + lv) * DI_ + d4]) = ay;
    *reinterpret_cast<float4*>(&p.xs[(base + (size_t)4 * L_ + (L_ - 1 - lv)) * DI_ + d4]) = ay;
    *reinterpret_cast<float4*>(&p.xs[(base + (size_t)2 * L_ + lv2) * DI_ + d4]) = ay;
    *reinterpret_cast<float4*>(&p.xs[(base + (size_t)5 * L_ + (L_ - 1 - lv2)) * DI_ + d4]) = ay;
  }
  gbar(cnt, gen);

  // ================= P3: x_dbl GEMM (864 tiles of 32 rows) =================
  {
    float* As = smem;          // [32][33]
    float* Ws = smem + 1056;   // [32][48]
    for (int tile = blockIdx.x; tile < B_ * K_ * L_ / 32; tile += GRID) {
      int row0 = tile * 32;
      int k = (row0 / L_) % K_;
      int tm = tid >> 4, tn = tid & 15;
      float acc[2][3];
#pragma unroll
      for (int i = 0; i < 2; ++i)
#pragma unroll
        for (int j = 0; j < 3; ++j) acc[i][j] = 0.f;
      for (int k0 = 0; k0 < DI_; k0 += 32) {
        {
          int r = tid >> 3, c4 = (tid & 7) << 2;
          float4 v = *reinterpret_cast<const float4*>(
              &p.xs[(size_t)(row0 + r) * DI_ + k0 + c4]);
          As[r * 33 + c4] = v.x; As[r * 33 + c4 + 1] = v.y;
          As[r * 33 + c4 + 2] = v.z; As[r * 33 + c4 + 3] = v.w;
        }
#pragma unroll
        for (int it = 0; it < 2; ++it) {
          int i = tid + it * 256;
          if (i < 384) {
            int r = i / 12, c4 = (i % 12) << 2;
            float4 v = *reinterpret_cast<const float4*>(
                &p.xpwT[((size_t)k * DI_ + k0 + r) * NPAD + c4]);
            Ws[r * 48 + c4] = v.x; Ws[r * 48 + c4 + 1] = v.y;
            Ws[r * 48 + c4 + 2] = v.z; Ws[r * 48 + c4 + 3] = v.w;
          }
        }
        __syncthreads();
#pragma unroll
        for (int kk = 0; kk < 32; ++kk) {
          float a0 = As[(tm * 2 + 0) * 33 + kk], a1 = As[(tm * 2 + 1) * 33 + kk];
          float w0 = Ws[kk * 48 + tn * 3 + 0], w1 = Ws[kk * 48 + tn * 3 + 1],
                w2 = Ws[kk * 48 + tn * 3 + 2];
          acc[0][0] += a0 * w0; acc[0][1] += a0 * w1; acc[0][2] += a0 * w2;
          acc[1][0] += a1 * w0; acc[1][1] += a1 * w1; acc[1][2] += a1 * w2;
        }
        __syncthreads();
      }
#pragma unroll
      for (int i = 0; i < 2; ++i) {
        int row = row0 + tm * 2 + i;
#pragma unroll
        for (int j = 0; j < 3; ++j) {
          int cc = tn * 3 + j;
          float v = acc[i][j];
          if (cc < RK_) p.dts[(size_t)row * RK_ + cc] = v;
          else if (cc < RK_ + NS_) p.Bsb[(size_t)row * NS_ + (cc - RK_)] = v;
          else if (cc < NPROJ) p.Csb[(size_t)row * NS_ + (cc - RK_ - NS_)] = v;
        }
      }
    }
  }
  gbar(cnt, gen);

  // ================= P4: scan pass 1 (1152 chunks x 192 lanes) =================
  for (int i = gtid; i < B_ * K_ * C_ * DI_; i += gsize) {
    int chunk = i / DI_, d = i % DI_;
    int bk = chunk / C_, c = chunk % C_;
    int k = bk % K_;
    float A[NS_];
#pragma unroll
    for (int n = 0; n < NS_; ++n)
      A[n] = -__expf(p.alogs[((size_t)k * DI_ + d) * NS_ + n]);
    float wdt[RK_];
#pragma unroll
    for (int r = 0; r < RK_; ++r) wdt[r] = p.dtw[((size_t)k * DI_ + d) * RK_ + r];
    float bias = p.dtb[k * DI_ + d];
    float S[NS_];
#pragma unroll
    for (int n = 0; n < NS_; ++n) S[n] = 0.f;
    float sum_dl = 0.f;
    size_t base = (size_t)bk * L_ + (size_t)c * LC_;
    for (int l = 0; l < LC_; ++l) {
      float dl = delta_of(p.dts + (base + l) * RK_, wdt, bias);
      float u = p.xs[(base + l) * DI_ + d];
      float du = dl * u;
      sum_dl += dl;
      const float* Bp = p.Bsb + (base + l) * NS_;
#pragma unroll
      for (int n = 0; n < NS_; ++n) {
        float e = __expf(dl * A[n]);
        S[n] = e * S[n] + du * Bp[n];
      }
    }
    p.Sdl[(size_t)chunk * DI_ + d] = sum_dl;
    size_t ob = (size_t)chunk * NS_ * DI_ + d;
#pragma unroll
    for (int n = 0; n < NS_; ++n) p.SHin[ob + (size_t)n * DI_] = S[n];
  }
  gbar(cnt, gen);

  // ================= P5: chunk-level scan (in-place S -> h_in) =================
  for (int i = gtid; i < B_ * K_ * NS_ * DI_; i += gsize) {
    int bkn = i / DI_, d = i % DI_;
    int bk = bkn / NS_, n = bkn % NS_;
    int k = bk % K_;
    float A = -__expf(p.alogs[((size_t)k * DI_ + d) * NS_ + n]);
    float h = 0.f;
    for (int c = 0; c < C_; ++c) {
      size_t idx = ((size_t)(bk * C_ + c) * NS_ + n) * DI_ + d;
      float s = p.SHin[idx];
      float pp = __expf(A * p.Sdl[(size_t)(bk * C_ + c) * DI_ + d]);
      p.SHin[idx] = h;
      h = pp * h + s;
    }
  }
  gbar(cnt, gen);

  // ================= P6: scan pass 3 -> out_y =================
  for (int i = gtid; i < B_ * K_ * C_ * DI_; i += gsize) {
    int chunk = i / DI_, d = i % DI_;
    int bk = chunk / C_, c = chunk % C_;
    int k = bk % K_;
    float A[NS_];
#pragma unroll
    for (int n = 0; n < NS_; ++n)
      A[n] = -__expf(p.alogs[((size_t)k * DI_ + d) * NS_ + n]);
    float wdt[RK_];
#pragma unroll
    for (int r = 0; r < RK_; ++r) wdt[r] = p.dtw[((size_t)k * DI_ + d) * RK_ + r];
    float bias = p.dtb[k * DI_ + d];
    float Dk = p.Dsp[k * DI_ + d];
    float h[NS_];
    size_t hb = (size_t)chunk * NS_ * DI_ + d;
#pragma unroll
    for (int n = 0; n < NS_; ++n) h[n] = p.SHin[hb + (size_t)n * DI_];
    size_t base = (size_t)bk * L_ + (size_t)c * LC_;
    for (int l = 0; l < LC_; ++l) {
      float dl = delta_of(p.dts + (base + l) * RK_, wdt, bias);
      float u = p.xs[(base + l) * DI_ + d];
      float du = dl * u;
      const float* Bp = p.Bsb + (base + l) * NS_;
      const float* Cp = p.Csb + (base + l) * NS_;
      float yacc = 0.f;
#pragma unroll
      for (int n = 0; n < NS_; ++n) {
        h[n] = __expf(dl * A[n]) * h[n] + du * Bp[n];
        yacc += h[n] * Cp[n];
      }
      p.out_y[(base + l) * DI_ + d] = yacc + Dk * u;
    }
  }
  gbar(cnt, gen);

  // ================= P7: merge + LN + gate + out-proj (432 tiles) =================
  {
    float* Gs = smem;            // [32][196]
    float* Ws2 = smem + 6272;    // [32][97]
    constexpr int BPS = (B_ * L_) / 32;   // 144
    for (int tile = blockIdx.x; tile < 3 * BPS; tile += GRID) {
      int m = tile / BPS;
      int r0 = (tile % BPS) * 32;
      {
        int row = tid >> 3, t8 = tid & 7;
        int bl = r0 + row;
        int b = bl / L_, lp = bl % L_;
        int h = lp / W_, w = lp % W_;
        int l0;
        if (m == 0) l0 = lp;
        else if (m == 1) l0 = w * H_ + h;
        else l0 = ((w - h + W_) % W_) * H_ + h;
        size_t basef = ((size_t)b * K_ + m) * L_;
        size_t baser = ((size_t)b * K_ + m + 3) * L_;
        const float* pf = p.out_y + (basef + l0) * DI_;
        const float* pr = p.out_y + (baser + (size_t)(L_ - 1 - l0)) * DI_;
        float s = 0.f, s2 = 0.f;
#pragma unroll
        for (int j = 0; j < 6; ++j) {
          int c4 = t8 * 24 + j * 4;
          float4 a = *reinterpret_cast<const float4*>(&pf[c4]);
          float4 bb = *reinterpret_cast<const float4*>(&pr[c4]);
          float4 t;
          t.x = a.x + bb.x; t.y = a.y + bb.y; t.z = a.z + bb.z; t.w = a.w + bb.w;
          s += t.x + t.y + t.z + t.w;
          s2 += t.x * t.x + t.y * t.y + t.z * t.z + t.w * t.w;
          *reinterpret_cast<float4*>(&Gs[row * 196 + c4]) = t;
        }
        s += __shfl_xor(s, 1, 64);  s2 += __shfl_xor(s2, 1, 64);
        s += __shfl_xor(s, 2, 64);  s2 += __shfl_xor(s2, 2, 64);
        s += __shfl_xor(s, 4, 64);  s2 += __shfl_xor(s2, 4, 64);
        float mu = s * (1.f / DI_);
        float var = fmaxf(s2 * (1.f / DI_) - mu * mu, 0.f);
        float rs = rsqrtf(var + 1e-5f);
        const float* zp = p.zg + (size_t)bl * DI_;
#pragma unroll
        for (int j = 0; j < 6; ++j) {
          int c4 = t8 * 24 + j * 4;
          float4 t = *reinterpret_cast<const float4*>(&Gs[row * 196 + c4]);
          float4 zv = *reinterpret_cast<const float4*>(&zp[c4]);
          t.x = ((t.x - mu) * rs * p.lnw[c4 + 0] + p.lnb[c4 + 0]) * zv.x;
          t.y = ((t.y - mu) * rs * p.lnw[c4 + 1] + p.lnb[c4 + 1]) * zv.y;
          t.z = ((t.z - mu) * rs * p.lnw[c4 + 2] + p.lnb[c4 + 2]) * zv.z;
          t.w = ((t.w - mu) * rs * p.lnw[c4 + 3] + p.lnb[c4 + 3]) * zv.w;
          *reinterpret_cast<float4*>(&Gs[row * 196 + c4]) = t;
        }
      }
      __syncthreads();

      int tm = tid >> 4, tn = tid & 15;
      float acc[2][6];
#pragma unroll
      for (int i = 0; i < 2; ++i)
#pragma unroll
        for (int j = 0; j < 6; ++j) acc[i][j] = 0.f;
      for (int k0 = 0; k0 < DI_; k0 += 32) {
#pragma unroll
        for (int it = 0; it < 3; ++it) {
          int i = tid + it * 256;
          int r = i / 24, c4 = (i % 24) << 2;
          float4 v = *reinterpret_cast<const float4*>(
              &p.wT[(size_t)(k0 + r) * DM_ + c4]);
          Ws2[r * 97 + c4] = v.x; Ws2[r * 97 + c4 + 1] = v.y;
          Ws2[r * 97 + c4 + 2] = v.z; Ws2[r * 97 + c4 + 3] = v.w;
        }
        __syncthreads();
#pragma unroll
        for (int kk = 0; kk < 32; ++kk) {
          float a0 = Gs[(tm * 2 + 0) * 196 + k0 + kk];
          float a1 = Gs[(tm * 2 + 1) * 196 + k0 + kk];
          float w[6];
#pragma unroll
          for (int j = 0; j < 6; ++j) w[j] = Ws2[kk * 97 + tn * 6 + j];
#pragma unroll
          for (int j = 0; j < 6; ++j) { acc[0][j] += a0 * w[j]; acc[1][j] += a1 * w[j]; }
        }
        __syncthreads();
      }
      size_t obase = ((size_t)m * (B_ * L_) + r0) * DM_;
#pragma unroll
      for (int i = 0; i < 2; ++i) {
        size_t ob = obase + (size_t)(tm * 2 + i) * DM_ + tn * 6;
#pragma unroll
        for (int j = 0; j < 6; ++j) p.out[ob + j] = acc[i][j];
      }
    }
  }
}

}  // namespace

extern "C" void kernel_launch(void* const* d_in, const int* in_sizes, int n_in,
                              void* d_out, int out_size, void* d_ws, size_t ws_size,
                              hipStream_t stream) {
  MegaP p;
  p.x = (const float*)d_in[0];
  p.y = (const float*)d_in[1];
  p.kin = (const float*)d_in[2];
  p.inpw = (const float*)d_in[3];
  p.convw = (const float*)d_in[4];
  p.convb = (const float*)d_in[5];
  p.xpw = (const float*)d_in[6];
  p.dtw = (const float*)d_in[7];
  p.dtb = (const float*)d_in[8];
  p.alogs = (const float*)d_in[9];
  p.Dsp = (const float*)d_in[10];
  p.lnw = (const float*)d_in[11];
  p.lnb = (const float*)d_in[12];
  p.opw = (const float*)d_in[13];
  p.out = (float*)d_out;

  p.bar = (unsigned*)d_ws;
  float* ws = (float*)((char*)d_ws + 256);
  const size_t BLD = (size_t)B_ * L_ * DI_;
  const size_t BKLD = (size_t)B_ * K_ * L_ * DI_;
  const size_t BKLN = (size_t)B_ * K_ * L_ * NS_;
  const size_t PSN = (size_t)B_ * K_ * C_ * NS_ * DI_;
  p.xv = ws;     ws += BLD;
  p.yv = ws;     ws += BLD;
  p.zg = ws;     ws += BLD;
  p.xs = ws;     ws += BKLD;
  p.Bsb = ws;    ws += BKLN;
  p.Csb = ws;    ws += BKLN;
  p.out_y = ws;  ws += BKLD;
  p.SHin = ws;   ws += PSN;
  p.Sdl = ws;    ws += (size_t)B_ * K_ * C_ * DI_;
  p.wT = ws;     ws += (size_t)DI_ * DM_;
  p.xpwT = ws;   ws += (size_t)K_ * DI_ * NPAD;
  p.wInT = ws;   ws += (size_t)DM_ * 2 * DI_;
  p.dts = ws;    ws += (size_t)B_ * K_ * L_ * RK_;
  p.cwT = ws;    ws += (size_t)9 * DI_;

  hipMemsetAsync(d_ws, 0, 256, stream);   // barrier state
  k_mega<<<dim3(GRID), dim3(NTHR), 0, stream>>>(p);
}

// Round 11
// 162.585 us; speedup vs baseline: 9.6096x; 9.6096x over previous
//
#include <hip/hip_runtime.h>
#include <hip/hip_bf16.h>

namespace {

constexpr int B_ = 2, H_ = 48, W_ = 48, DM_ = 96, DI_ = 192, NS_ = 16, RK_ = 6, K_ = 6;
constexpr int L_ = H_ * W_;
constexpr int C_ = 144;           // chunks per (b,k) stream
constexpr int LC_ = L_ / C_;      // 16 steps per chunk
constexpr int NPROJ = RK_ + 2 * NS_;  // 38
constexpr int NPAD = 48;

__device__ __forceinline__ float sigmoidf_(float x) { return 1.f / (1.f + __expf(-x)); }

// softplus(dtb + dts(row)·dtw(d)) — evaluated identically in scan1 and scan3.
__device__ __forceinline__ float delta_of(const float* __restrict__ dp,
                                          const float* __restrict__ wdt,
                                          float bias) {
  float s = bias;
#pragma unroll
  for (int r = 0; r < RK_; ++r) s += dp[r] * wdt[r];
  return (s > 20.f) ? s : __logf(1.f + __expf(s));
}

// ---------------------------------------------------------------------------
// K1: in_proj tiled GEMM, weights staged transposed straight from in_proj_w.
// IM=32 -> grid 432, block 256.
// ---------------------------------------------------------------------------
constexpr int IM = 32, IBK = 32;
__global__ void __launch_bounds__(256) k_inproj2(
    const float* __restrict__ x, const float* __restrict__ y,
    const float* __restrict__ kin, const float* __restrict__ inpw,
    float* __restrict__ xv, float* __restrict__ yv, float* __restrict__ zg) {
  __shared__ float As[IM][IBK + 1];
  __shared__ float Ws[IBK][DI_ + 1];
  int tid = threadIdx.x;
  constexpr int BPS = (B_ * L_) / IM;   // 144 blocks per stream
  int s = blockIdx.x / BPS;
  int row0 = (blockIdx.x % BPS) * IM;
  const float* src = (s == 0) ? x : (s == 1) ? y : kin;
  float* dst = (s == 0) ? xv : (s == 1) ? yv : zg;
  int nbase = (s == 2) ? DI_ : 0;
  int tm = tid >> 4, tn = tid & 15;     // 16 x 16
  float acc[2][12];
#pragma unroll
  for (int i = 0; i < 2; ++i)
#pragma unroll
    for (int j = 0; j < 12; ++j) acc[i][j] = 0.f;

  for (int k0 = 0; k0 < DM_; k0 += IBK) {
    {  // A tile: 32x32 = 256 float4, 1/thread
      int r = tid >> 3, c4 = (tid & 7) << 2;
      const float4 v = *reinterpret_cast<const float4*>(
          &src[(size_t)(row0 + r) * DM_ + k0 + c4]);
      As[r][c4] = v.x; As[r][c4 + 1] = v.y; As[r][c4 + 2] = v.z; As[r][c4 + 3] = v.w;
    }
    // W tile transposed on the fly: Ws[kk][col] = inpw[(nbase+col)*DM + k0+kk]
#pragma unroll
    for (int it = 0; it < 6; ++it) {
      int i = tid + it * 256;        // [0,1536)
      int col = i >> 3, k4 = (i & 7) << 2;
      const float4 v = *reinterpret_cast<const float4*>(
          &inpw[(size_t)(nbase + col) * DM_ + k0 + k4]);
      Ws[k4 + 0][col] = v.x; Ws[k4 + 1][col] = v.y;
      Ws[k4 + 2][col] = v.z; Ws[k4 + 3][col] = v.w;
    }
    __syncthreads();
#pragma unroll
    for (int kk = 0; kk < IBK; ++kk) {
      float a0 = As[tm * 2 + 0][kk], a1 = As[tm * 2 + 1][kk];
      float w[12];
#pragma unroll
      for (int j = 0; j < 12; ++j) w[j] = Ws[kk][tn * 12 + j];
#pragma unroll
      for (int j = 0; j < 12; ++j) {
        acc[0][j] += a0 * w[j];
        acc[1][j] += a1 * w[j];
      }
    }
    __syncthreads();
  }
#pragma unroll
  for (int i = 0; i < 2; ++i) {
    size_t ob = (size_t)(row0 + tm * 2 + i) * DI_ + tn * 12;
#pragma unroll
    for (int j4 = 0; j4 < 3; ++j4) {
      float4 v;
      v.x = acc[i][j4 * 4 + 0]; v.y = acc[i][j4 * 4 + 1];
      v.z = acc[i][j4 * 4 + 2]; v.w = acc[i][j4 * 4 + 3];
      if (s == 2) {
        v.x *= sigmoidf_(v.x); v.y *= sigmoidf_(v.y);
        v.z *= sigmoidf_(v.z); v.w *= sigmoidf_(v.w);
      }
      *reinterpret_cast<float4*>(&dst[ob + j4 * 4]) = v;
    }
  }
}

// ---------------------------------------------------------------------------
// K2: conv 3x3 + SiLU, float4, 4 pixels/block; weights transposed into LDS.
// grid = B*L/4 = 1152, 192 threads.
// ---------------------------------------------------------------------------
__global__ void __launch_bounds__(192) k_conv_xs(
    const float* __restrict__ xv, const float* __restrict__ yv,
    const float* __restrict__ cw, const float* __restrict__ cb,
    float* __restrict__ xs) {
  __shared__ float scw[9 * DI_];
  int tid = threadIdx.x;
  for (int i = tid; i < 9 * DI_; i += 192) {
    int d = i / 9, j = i % 9;
    scw[j * DI_ + d] = cw[i];
  }
  __syncthreads();
  int p = tid / 48, q = tid % 48;
  int gl = blockIdx.x * 4 + p;
  int b = gl / L_, l = gl % L_;
  int h = l / W_, w = l % W_;
  int d4 = q << 2;
  float4 ax = *reinterpret_cast<const float4*>(&cb[d4]);
  float4 ay = ax;
#pragma unroll
  for (int kh = 0; kh < 3; ++kh) {
    int hh = h + kh - 1;
    if ((unsigned)hh >= (unsigned)H_) continue;
#pragma unroll
    for (int kw = 0; kw < 3; ++kw) {
      int ww = w + kw - 1;
      if ((unsigned)ww >= (unsigned)W_) continue;
      float4 wk = *reinterpret_cast<const float4*>(&scw[(kh * 3 + kw) * DI_ + d4]);
      size_t idx = ((size_t)b * L_ + hh * W_ + ww) * DI_ + d4;
      float4 vx = *reinterpret_cast<const float4*>(&xv[idx]);
      float4 vy = *reinterpret_cast<const float4*>(&yv[idx]);
      ax.x += vx.x * wk.x; ax.y += vx.y * wk.y; ax.z += vx.z * wk.z; ax.w += vx.w * wk.w;
      ay.x += vy.x * wk.x; ay.y += vy.y * wk.y; ay.z += vy.z * wk.z; ay.w += vy.w * wk.w;
    }
  }
  ax.x *= sigmoidf_(ax.x); ax.y *= sigmoidf_(ax.y);
  ax.z *= sigmoidf_(ax.z); ax.w *= sigmoidf_(ax.w);
  ay.x *= sigmoidf_(ay.x); ay.y *= sigmoidf_(ay.y);
  ay.z *= sigmoidf_(ay.z); ay.w *= sigmoidf_(ay.w);
  size_t base = (size_t)b * K_ * L_;
  int lv = w * H_ + h;
  int lv2 = ((w - h + W_) % W_) * H_ + h;
#define STORE6(kk, pos, val) \
  *reinterpret_cast<float4*>(&xs[(base + (size_t)(kk) * L_ + (pos)) * DI_ + d4]) = (val)
  STORE6(0, l, ax);
  STORE6(3, L_ - 1 - l, ax);
  STORE6(1, lv, ay);
  STORE6(4, L_ - 1 - lv, ay);
  STORE6(2, lv2, ay);
  STORE6(5, L_ - 1 - lv2, ay);
#undef STORE6
}

// ---------------------------------------------------------------------------
// K4: x_dbl GEMM, weights staged transposed straight from x_proj_w.
// M tiles of 32, N = 48(pad of 38), K = 192.  grid 864, block 256.
// ---------------------------------------------------------------------------
constexpr int XM = 32, XBK = 32;
__global__ void __launch_bounds__(256) k_xdbl3(
    const float* __restrict__ xs, const float* __restrict__ xpw,
    float* __restrict__ dts, float* __restrict__ Bsb, float* __restrict__ Csb) {
  __shared__ float As[XM][XBK + 1];
  __shared__ float Ws[XBK][NPAD];
  int tid = threadIdx.x;
  int row0 = blockIdx.x * XM;
  int k = (row0 / L_) % K_;
  int tm = tid >> 4, tn = tid & 15;
  // zero the pad columns once (never written afterwards)
  for (int i = tid; i < XBK * (NPAD - NPROJ); i += 256) {
    int kk = i / (NPAD - NPROJ), c = NPROJ + i % (NPAD - NPROJ);
    Ws[kk][c] = 0.f;
  }
  float acc[2][3];
#pragma unroll
  for (int i = 0; i < 2; ++i)
#pragma unroll
    for (int j = 0; j < 3; ++j) acc[i][j] = 0.f;

  for (int k0 = 0; k0 < DI_; k0 += XBK) {
    {
      int r = tid >> 3, c4 = (tid & 7) << 2;
      const float4 v = *reinterpret_cast<const float4*>(
          &xs[(size_t)(row0 + r) * DI_ + k0 + c4]);
      As[r][c4] = v.x; As[r][c4 + 1] = v.y; As[r][c4 + 2] = v.z; As[r][c4 + 3] = v.w;
    }
    // Ws[kk][c] = xpw[(k*38+c)*DI + k0+kk], float4 along kk
#pragma unroll
    for (int it = 0; it < 2; ++it) {
      int i = tid + it * 256;
      if (i < NPROJ * 8) {
        int c = i >> 3, k4 = (i & 7) << 2;
        const float4 v = *reinterpret_cast<const float4*>(
            &xpw[((size_t)k * NPROJ + c) * DI_ + k0 + k4]);
        Ws[k4 + 0][c] = v.x; Ws[k4 + 1][c] = v.y;
        Ws[k4 + 2][c] = v.z; Ws[k4 + 3][c] = v.w;
      }
    }
    __syncthreads();
#pragma unroll
    for (int kk = 0; kk < XBK; ++kk) {
      float a0 = As[tm * 2 + 0][kk], a1 = As[tm * 2 + 1][kk];
      float w0 = Ws[kk][tn * 3 + 0], w1 = Ws[kk][tn * 3 + 1], w2 = Ws[kk][tn * 3 + 2];
      acc[0][0] += a0 * w0; acc[0][1] += a0 * w1; acc[0][2] += a0 * w2;
      acc[1][0] += a1 * w0; acc[1][1] += a1 * w1; acc[1][2] += a1 * w2;
    }
    __syncthreads();
  }
#pragma unroll
  for (int i = 0; i < 2; ++i) {
    int row = row0 + tm * 2 + i;
#pragma unroll
    for (int j = 0; j < 3; ++j) {
      int cc = tn * 3 + j;
      float v = acc[i][j];
      if (cc < RK_) dts[(size_t)row * RK_ + cc] = v;
      else if (cc < RK_ + NS_) Bsb[(size_t)row * NS_ + (cc - RK_)] = v;
      else if (cc < NPROJ) Csb[(size_t)row * NS_ + (cc - RK_ - NS_)] = v;
    }
  }
}

// ---------------------------------------------------------------------------
// K5a: chunked scan pass 1.  B/dts rows LDS-staged per chunk.
// grid = B*K*C_ = 1728, 192 thr.
// ---------------------------------------------------------------------------
__global__ void __launch_bounds__(192) k_scan1(
    const float* __restrict__ dts, const float* __restrict__ dtw,
    const float* __restrict__ dtb, const float* __restrict__ xs,
    const float* __restrict__ Bsb, const float* __restrict__ A_logs,
    float* __restrict__ Sdl, float* __restrict__ SHin) {
  __shared__ float sB[LC_ * NS_];    // 256
  __shared__ float sdt[LC_ * RK_];   // 96
  int blk = blockIdx.x;            // bk*C_ + c
  int bk = blk / C_, c = blk % C_;
  int k = bk % K_;
  int d = threadIdx.x;
  size_t base = (size_t)bk * L_ + (size_t)c * LC_;
  for (int i = d; i < LC_ * NS_; i += 192) sB[i] = Bsb[base * NS_ + i];
  for (int i = d; i < LC_ * RK_; i += 192) sdt[i] = dts[base * RK_ + i];
  float A[NS_];
#pragma unroll
  for (int n = 0; n < NS_; ++n) A[n] = -__expf(A_logs[((size_t)k * DI_ + d) * NS_ + n]);
  float wdt[RK_];
#pragma unroll
  for (int r = 0; r < RK_; ++r) wdt[r] = dtw[((size_t)k * DI_ + d) * RK_ + r];
  float bias = dtb[k * DI_ + d];
  float S[NS_];
#pragma unroll
  for (int n = 0; n < NS_; ++n) S[n] = 0.f;
  float sum_dl = 0.f;
  __syncthreads();
  for (int l = 0; l < LC_; ++l) {
    float dl = delta_of(&sdt[l * RK_], wdt, bias);
    float u = xs[(base + l) * DI_ + d];
    float du = dl * u;
    sum_dl += dl;
    const float* Bp = &sB[l * NS_];
#pragma unroll
    for (int n = 0; n < NS_; ++n) {
      float e = __expf(dl * A[n]);
      S[n] = e * S[n] + du * Bp[n];
    }
  }
  Sdl[(size_t)blk * DI_ + d] = sum_dl;
  size_t ob = (size_t)blk * NS_ * DI_ + d;
#pragma unroll
  for (int n = 0; n < NS_; ++n) SHin[ob + (size_t)n * DI_] = S[n];
}

// ---------------------------------------------------------------------------
// K5b: chunk-level scan, parallel over (bk, n).  grid = B*K*NS = 192.
// ---------------------------------------------------------------------------
__global__ void __launch_bounds__(192) k_scan2(
    const float* __restrict__ Sdl, const float* __restrict__ A_logs,
    float* __restrict__ SHin) {
  int bkn = blockIdx.x;            // bk*NS + n
  int bk = bkn / NS_, n = bkn % NS_;
  int k = bk % K_;
  int d = threadIdx.x;
  float A = -__expf(A_logs[((size_t)k * DI_ + d) * NS_ + n]);
  float h = 0.f;
  for (int c = 0; c < C_; ++c) {
    size_t i = ((size_t)(bk * C_ + c) * NS_ + n) * DI_ + d;
    float s = SHin[i];
    float p = __expf(A * Sdl[(size_t)(bk * C_ + c) * DI_ + d]);
    SHin[i] = h;
    h = p * h + s;
  }
}

// ---------------------------------------------------------------------------
// K5c: chunked scan pass 3.  B/C/dts rows LDS-staged.  grid = 1728, 192 thr.
// ---------------------------------------------------------------------------
__global__ void __launch_bounds__(192) k_scan3(
    const float* __restrict__ dts, const float* __restrict__ dtw,
    const float* __restrict__ dtb, const float* __restrict__ xs,
    const float* __restrict__ Bsb, const float* __restrict__ Csb,
    const float* __restrict__ A_logs, const float* __restrict__ Ds,
    const float* __restrict__ SHin, float* __restrict__ out_y) {
  __shared__ float sB[LC_ * NS_];
  __shared__ float sC[LC_ * NS_];
  __shared__ float sdt[LC_ * RK_];
  int blk = blockIdx.x;            // bk*C_ + c
  int bk = blk / C_, c = blk % C_;
  int k = bk % K_;
  int d = threadIdx.x;
  size_t base = (size_t)bk * L_ + (size_t)c * LC_;
  for (int i = d; i < LC_ * NS_; i += 192) {
    sB[i] = Bsb[base * NS_ + i];
    sC[i] = Csb[base * NS_ + i];
  }
  for (int i = d; i < LC_ * RK_; i += 192) sdt[i] = dts[base * RK_ + i];
  float A[NS_];
#pragma unroll
  for (int n = 0; n < NS_; ++n) A[n] = -__expf(A_logs[((size_t)k * DI_ + d) * NS_ + n]);
  float wdt[RK_];
#pragma unroll
  for (int r = 0; r < RK_; ++r) wdt[r] = dtw[((size_t)k * DI_ + d) * RK_ + r];
  float bias = dtb[k * DI_ + d];
  float Dk = Ds[k * DI_ + d];
  float h[NS_];
  size_t hb = (size_t)blk * NS_ * DI_ + d;
#pragma unroll
  for (int n = 0; n < NS_; ++n) h[n] = SHin[hb + (size_t)n * DI_];
  __syncthreads();
  for (int l = 0; l < LC_; ++l) {
    float dl = delta_of(&sdt[l * RK_], wdt, bias);
    float u = xs[(base + l) * DI_ + d];
    float du = dl * u;
    const float* Bp = &sB[l * NS_];
    const float* Cp = &sC[l * NS_];
    float yacc = 0.f;
#pragma unroll
    for (int n = 0; n < NS_; ++n) {
      h[n] = __expf(dl * A[n]) * h[n] + du * Bp[n];
      yacc += h[n] * Cp[n];
    }
    out_y[(base + l) * DI_ + d] = yacc + Dk * u;
  }
}

// ---------------------------------------------------------------------------
// K6: merge + LN + gate -> LDS, out-proj GEMM from LDS; weights staged
// transposed straight from out_proj_w.  MT=32, grid 432, block 256.
// ---------------------------------------------------------------------------
constexpr int MT = 32, GS_ = 196;
__global__ void __launch_bounds__(256) k_head2(
    const float* __restrict__ out_y, const float* __restrict__ zg,
    const float* __restrict__ lnw, const float* __restrict__ lnb,
    const float* __restrict__ opw, float* __restrict__ out) {
  __shared__ float Gs[MT][GS_];
  __shared__ float Ws[32][DM_ + 1];
  int tid = threadIdx.x;
  constexpr int BPS = (B_ * L_) / MT;  // 144
  int m = blockIdx.x / BPS;
  int r0 = (blockIdx.x % BPS) * MT;

  {  // phase 1: 8 threads/row
    int row = tid >> 3, t8 = tid & 7;
    int bl = r0 + row;
    int b = bl / L_, lp = bl % L_;
    int h = lp / W_, w = lp % W_;
    int l0;
    if (m == 0) l0 = lp;
    else if (m == 1) l0 = w * H_ + h;
    else l0 = ((w - h + W_) % W_) * H_ + h;
    size_t basef = ((size_t)b * K_ + m) * L_;
    size_t baser = ((size_t)b * K_ + m + 3) * L_;
    const float* pf = out_y + (basef + l0) * DI_;
    const float* pr = out_y + (baser + (size_t)(L_ - 1 - l0)) * DI_;
    float s = 0.f, s2 = 0.f;
#pragma unroll
    for (int j = 0; j < 6; ++j) {
      int c4 = t8 * 24 + j * 4;
      float4 a = *reinterpret_cast<const float4*>(&pf[c4]);
      float4 bb = *reinterpret_cast<const float4*>(&pr[c4]);
      float4 t;
      t.x = a.x + bb.x; t.y = a.y + bb.y; t.z = a.z + bb.z; t.w = a.w + bb.w;
      s += t.x + t.y + t.z + t.w;
      s2 += t.x * t.x + t.y * t.y + t.z * t.z + t.w * t.w;
      *reinterpret_cast<float4*>(&Gs[row][c4]) = t;
    }
    s += __shfl_xor(s, 1, 64);  s2 += __shfl_xor(s2, 1, 64);
    s += __shfl_xor(s, 2, 64);  s2 += __shfl_xor(s2, 2, 64);
    s += __shfl_xor(s, 4, 64);  s2 += __shfl_xor(s2, 4, 64);
    float mu = s * (1.f / DI_);
    float var = fmaxf(s2 * (1.f / DI_) - mu * mu, 0.f);
    float rs = rsqrtf(var + 1e-5f);
    const float* zp = zg + (size_t)bl * DI_;
#pragma unroll
    for (int j = 0; j < 6; ++j) {
      int c4 = t8 * 24 + j * 4;
      float4 t = *reinterpret_cast<const float4*>(&Gs[row][c4]);
      float4 zv = *reinterpret_cast<const float4*>(&zp[c4]);
      t.x = ((t.x - mu) * rs * lnw[c4 + 0] + lnb[c4 + 0]) * zv.x;
      t.y = ((t.y - mu) * rs * lnw[c4 + 1] + lnb[c4 + 1]) * zv.y;
      t.z = ((t.z - mu) * rs * lnw[c4 + 2] + lnb[c4 + 2]) * zv.z;
      t.w = ((t.w - mu) * rs * lnw[c4 + 3] + lnb[c4 + 3]) * zv.w;
      *reinterpret_cast<float4*>(&Gs[row][c4]) = t;
    }
  }
  __syncthreads();

  int tm = tid >> 4, tn = tid & 15;
  float acc[2][6];
#pragma unroll
  for (int i = 0; i < 2; ++i)
#pragma unroll
    for (int j = 0; j < 6; ++j) acc[i][j] = 0.f;

  for (int k0 = 0; k0 < DI_; k0 += 32) {
    // Ws[kk][o] = opw[o*DI + k0+kk], float4 along kk
#pragma unroll
    for (int it = 0; it < 3; ++it) {
      int i = tid + it * 256;        // [0,768)
      int o = i >> 3, k4 = (i & 7) << 2;
      const float4 v = *reinterpret_cast<const float4*>(
          &opw[(size_t)o * DI_ + k0 + k4]);
      Ws[k4 + 0][o] = v.x; Ws[k4 + 1][o] = v.y;
      Ws[k4 + 2][o] = v.z; Ws[k4 + 3][o] = v.w;
    }
    __syncthreads();
#pragma unroll
    for (int kk = 0; kk < 32; ++kk) {
      float a0 = Gs[tm * 2 + 0][k0 + kk], a1 = Gs[tm * 2 + 1][k0 + kk];
      float w[6];
#pragma unroll
      for (int j = 0; j < 6; ++j) w[j] = Ws[kk][tn * 6 + j];
#pragma unroll
      for (int j = 0; j < 6; ++j) {
        acc[0][j] += a0 * w[j];
        acc[1][j] += a1 * w[j];
      }
    }
    __syncthreads();
  }
  size_t obase = ((size_t)m * (B_ * L_) + r0) * DM_;
#pragma unroll
  for (int i = 0; i < 2; ++i) {
    size_t ob = obase + (size_t)(tm * 2 + i) * DM_ + tn * 6;
#pragma unroll
    for (int j = 0; j < 6; ++j) out[ob + j] = acc[i][j];
  }
}

}  // namespace

extern "C" void kernel_launch(void* const* d_in, const int* in_sizes, int n_in,
                              void* d_out, int out_size, void* d_ws, size_t ws_size,
                              hipStream_t stream) {
  const float* x = (const float*)d_in[0];
  const float* y = (const float*)d_in[1];
  const float* kin = (const float*)d_in[2];
  const float* in_proj_w = (const float*)d_in[3];
  const float* conv_w = (const float*)d_in[4];
  const float* conv_b = (const float*)d_in[5];
  const float* x_proj_w = (const float*)d_in[6];
  const float* dt_w = (const float*)d_in[7];
  const float* dt_b = (const float*)d_in[8];
  const float* A_logs = (const float*)d_in[9];
  const float* Ds = (const float*)d_in[10];
  const float* ln_w = (const float*)d_in[11];
  const float* ln_b = (const float*)d_in[12];
  const float* out_proj_w = (const float*)d_in[13];
  float* out = (float*)d_out;

  float* ws = (float*)d_ws;
  const size_t BLD = (size_t)B_ * L_ * DI_;
  const size_t BKLD = (size_t)B_ * K_ * L_ * DI_;
  const size_t BKLN = (size_t)B_ * K_ * L_ * NS_;
  const size_t PSN = (size_t)B_ * K_ * C_ * NS_ * DI_;
  float* xv = ws;     ws += BLD;
  float* yv = ws;     ws += BLD;
  float* zg = ws;     ws += BLD;
  float* xs = ws;     ws += BKLD;
  float* Bsb = ws;    ws += BKLN;
  float* Csb = ws;    ws += BKLN;
  float* out_y = ws;  ws += BKLD;
  float* SHin = ws;   ws += PSN;
  float* Sdl = ws;    ws += (size_t)B_ * K_ * C_ * DI_;
  float* dts = ws;    ws += (size_t)B_ * K_ * L_ * RK_;

  k_inproj2<<<3 * B_ * L_ / IM, 256, 0, stream>>>(x, y, kin, in_proj_w, xv, yv, zg);
  k_conv_xs<<<B_ * L_ / 4, 192, 0, stream>>>(xv, yv, conv_w, conv_b, xs);
  k_xdbl3<<<B_ * K_ * L_ / XM, 256, 0, stream>>>(xs, x_proj_w, dts, Bsb, Csb);
  k_scan1<<<B_ * K_ * C_, 192, 0, stream>>>(dts, dt_w, dt_b, xs, Bsb, A_logs, Sdl, SHin);
  k_scan2<<<B_ * K_ * NS_, 192, 0, stream>>>(Sdl, A_logs, SHin);
  k_scan3<<<B_ * K_ * C_, 192, 0, stream>>>(dts, dt_w, dt_b, xs, Bsb, Csb, A_logs,
                                            Ds, SHin, out_y);
  k_head2<<<3 * B_ * L_ / MT, 256, 0, stream>>>(out_y, zg, ln_w, ln_b, out_proj_w, out);
}

// Round 12
// 161.343 us; speedup vs baseline: 9.6836x; 1.0077x over previous
//
#include <hip/hip_runtime.h>
#include <hip/hip_bf16.h>

namespace {

constexpr int B_ = 2, H_ = 48, W_ = 48, DM_ = 96, DI_ = 192, NS_ = 16, RK_ = 6, K_ = 6;
constexpr int L_ = H_ * W_;
constexpr int C_ = 144;           // chunks per (b,k) stream
constexpr int LC_ = L_ / C_;      // 16 steps per chunk
constexpr int NPROJ = RK_ + 2 * NS_;  // 38
constexpr int NPAD = 48;

__device__ __forceinline__ float sigmoidf_(float x) { return 1.f / (1.f + __expf(-x)); }

// softplus(dtb + dts(row)·dtw(d)) — evaluated identically in scan1 and scan3.
__device__ __forceinline__ float delta_of(const float* __restrict__ dp,
                                          const float* __restrict__ wdt,
                                          float bias) {
  float s = bias;
#pragma unroll
  for (int r = 0; r < RK_; ++r) s += dp[r] * wdt[r];
  return (s > 20.f) ? s : __logf(1.f + __expf(s));
}

// Row of xc/yc (pixel-major l = h*W+w) holding direction-k stream position pos.
//  k0/k3: xc row pos (k3 flipped).  k1/k4: col-major.  k2/k5: diagonal.
__device__ __forceinline__ int src_row(int k, int pos) {
  int pk = (k >= 3) ? (L_ - 1 - pos) : pos;
  int kk = (k >= 3) ? k - 3 : k;
  if (kk == 0) return pk;
  int h = pk % H_, wcol = pk / H_;        // pk = wcol*H + h
  if (kk == 1) return h * W_ + wcol;
  return h * W_ + (wcol + h) % W_;        // diag: orig col = (wcol+h)%W
}

// ---------------------------------------------------------------------------
// K1: in_proj tiled GEMM, weights staged transposed straight from in_proj_w.
// IM=32 -> grid 432, block 256.
// ---------------------------------------------------------------------------
constexpr int IM = 32, IBK = 32;
__global__ void __launch_bounds__(256) k_inproj2(
    const float* __restrict__ x, const float* __restrict__ y,
    const float* __restrict__ kin, const float* __restrict__ inpw,
    float* __restrict__ xv, float* __restrict__ yv, float* __restrict__ zg) {
  __shared__ float As[IM][IBK + 1];
  __shared__ float Ws[IBK][DI_ + 1];
  int tid = threadIdx.x;
  constexpr int BPS = (B_ * L_) / IM;   // 144 blocks per stream
  int s = blockIdx.x / BPS;
  int row0 = (blockIdx.x % BPS) * IM;
  const float* src = (s == 0) ? x : (s == 1) ? y : kin;
  float* dst = (s == 0) ? xv : (s == 1) ? yv : zg;
  int nbase = (s == 2) ? DI_ : 0;
  int tm = tid >> 4, tn = tid & 15;     // 16 x 16
  float acc[2][12];
#pragma unroll
  for (int i = 0; i < 2; ++i)
#pragma unroll
    for (int j = 0; j < 12; ++j) acc[i][j] = 0.f;

  for (int k0 = 0; k0 < DM_; k0 += IBK) {
    {  // A tile: 32x32 = 256 float4, 1/thread
      int r = tid >> 3, c4 = (tid & 7) << 2;
      const float4 v = *reinterpret_cast<const float4*>(
          &src[(size_t)(row0 + r) * DM_ + k0 + c4]);
      As[r][c4] = v.x; As[r][c4 + 1] = v.y; As[r][c4 + 2] = v.z; As[r][c4 + 3] = v.w;
    }
    // W tile transposed on the fly: Ws[kk][col] = inpw[(nbase+col)*DM + k0+kk]
#pragma unroll
    for (int it = 0; it < 6; ++it) {
      int i = tid + it * 256;        // [0,1536)
      int col = i >> 3, k4 = (i & 7) << 2;
      const float4 v = *reinterpret_cast<const float4*>(
          &inpw[(size_t)(nbase + col) * DM_ + k0 + k4]);
      Ws[k4 + 0][col] = v.x; Ws[k4 + 1][col] = v.y;
      Ws[k4 + 2][col] = v.z; Ws[k4 + 3][col] = v.w;
    }
    __syncthreads();
#pragma unroll
    for (int kk = 0; kk < IBK; ++kk) {
      float a0 = As[tm * 2 + 0][kk], a1 = As[tm * 2 + 1][kk];
      float w[12];
#pragma unroll
      for (int j = 0; j < 12; ++j) w[j] = Ws[kk][tn * 12 + j];
#pragma unroll
      for (int j = 0; j < 12; ++j) {
        acc[0][j] += a0 * w[j];
        acc[1][j] += a1 * w[j];
      }
    }
    __syncthreads();
  }
#pragma unroll
  for (int i = 0; i < 2; ++i) {
    size_t ob = (size_t)(row0 + tm * 2 + i) * DI_ + tn * 12;
#pragma unroll
    for (int j4 = 0; j4 < 3; ++j4) {
      float4 v;
      v.x = acc[i][j4 * 4 + 0]; v.y = acc[i][j4 * 4 + 1];
      v.z = acc[i][j4 * 4 + 2]; v.w = acc[i][j4 * 4 + 3];
      if (s == 2) {
        v.x *= sigmoidf_(v.x); v.y *= sigmoidf_(v.y);
        v.z *= sigmoidf_(v.z); v.w *= sigmoidf_(v.w);
      }
      *reinterpret_cast<float4*>(&dst[ob + j4 * 4]) = v;
    }
  }
}

// ---------------------------------------------------------------------------
// K2: conv 3x3 + SiLU -> xc, yc in pixel-major (b,l,d).  2 stores/thread.
// grid = B*L/4 = 1152, 192 threads.
// ---------------------------------------------------------------------------
__global__ void __launch_bounds__(192) k_conv2(
    const float* __restrict__ xv, const float* __restrict__ yv,
    const float* __restrict__ cw, const float* __restrict__ cb,
    float* __restrict__ xc, float* __restrict__ yc) {
  __shared__ float scw[9 * DI_];
  int tid = threadIdx.x;
  for (int i = tid; i < 9 * DI_; i += 192) {
    int d = i / 9, j = i % 9;
    scw[j * DI_ + d] = cw[i];
  }
  __syncthreads();
  int p = tid / 48, q = tid % 48;
  int gl = blockIdx.x * 4 + p;
  int b = gl / L_, l = gl % L_;
  int h = l / W_, w = l % W_;
  int d4 = q << 2;
  float4 ax = *reinterpret_cast<const float4*>(&cb[d4]);
  float4 ay = ax;
#pragma unroll
  for (int kh = 0; kh < 3; ++kh) {
    int hh = h + kh - 1;
    if ((unsigned)hh >= (unsigned)H_) continue;
#pragma unroll
    for (int kw = 0; kw < 3; ++kw) {
      int ww = w + kw - 1;
      if ((unsigned)ww >= (unsigned)W_) continue;
      float4 wk = *reinterpret_cast<const float4*>(&scw[(kh * 3 + kw) * DI_ + d4]);
      size_t idx = ((size_t)b * L_ + hh * W_ + ww) * DI_ + d4;
      float4 vx = *reinterpret_cast<const float4*>(&xv[idx]);
      float4 vy = *reinterpret_cast<const float4*>(&yv[idx]);
      ax.x += vx.x * wk.x; ax.y += vx.y * wk.y; ax.z += vx.z * wk.z; ax.w += vx.w * wk.w;
      ay.x += vy.x * wk.x; ay.y += vy.y * wk.y; ay.z += vy.z * wk.z; ay.w += vy.w * wk.w;
    }
  }
  ax.x *= sigmoidf_(ax.x); ax.y *= sigmoidf_(ax.y);
  ax.z *= sigmoidf_(ax.z); ax.w *= sigmoidf_(ax.w);
  ay.x *= sigmoidf_(ay.x); ay.y *= sigmoidf_(ay.y);
  ay.z *= sigmoidf_(ay.z); ay.w *= sigmoidf_(ay.w);
  size_t ob = (size_t)gl * DI_ + d4;
  *reinterpret_cast<float4*>(&xc[ob]) = ax;
  *reinterpret_cast<float4*>(&yc[ob]) = ay;
}

// ---------------------------------------------------------------------------
// K4: x_dbl GEMM; A-tile rows gathered via src_row from xc/yc.
// M tiles of 32 (within one k), N=48(pad of 38), K=192.  grid 864, block 256.
// ---------------------------------------------------------------------------
constexpr int XM = 32, XBK = 32;
__global__ void __launch_bounds__(256) k_xdbl3(
    const float* __restrict__ xc, const float* __restrict__ yc,
    const float* __restrict__ xpw,
    float* __restrict__ dts, float* __restrict__ Bsb, float* __restrict__ Csb) {
  __shared__ float As[XM][XBK + 1];
  __shared__ float Ws[XBK][NPAD];
  int tid = threadIdx.x;
  int row0 = blockIdx.x * XM;
  int b = row0 / (K_ * L_);
  int k = (row0 / L_) % K_;
  int pos0 = row0 % L_;
  const float* usrc = ((k == 0 || k == 3) ? xc : yc) + (size_t)b * L_ * DI_;
  int tm = tid >> 4, tn = tid & 15;
  for (int i = tid; i < XBK * (NPAD - NPROJ); i += 256) {
    int kk = i / (NPAD - NPROJ), c = NPROJ + i % (NPAD - NPROJ);
    Ws[kk][c] = 0.f;
  }
  float acc[2][3];
#pragma unroll
  for (int i = 0; i < 2; ++i)
#pragma unroll
    for (int j = 0; j < 3; ++j) acc[i][j] = 0.f;

  for (int k0 = 0; k0 < DI_; k0 += XBK) {
    {
      int r = tid >> 3, c4 = (tid & 7) << 2;
      int srow = src_row(k, pos0 + r);
      const float4 v = *reinterpret_cast<const float4*>(
          &usrc[(size_t)srow * DI_ + k0 + c4]);
      As[r][c4] = v.x; As[r][c4 + 1] = v.y; As[r][c4 + 2] = v.z; As[r][c4 + 3] = v.w;
    }
    // Ws[kk][c] = xpw[(k*38+c)*DI + k0+kk], float4 along kk
#pragma unroll
    for (int it = 0; it < 2; ++it) {
      int i = tid + it * 256;
      if (i < NPROJ * 8) {
        int c = i >> 3, k4 = (i & 7) << 2;
        const float4 v = *reinterpret_cast<const float4*>(
            &xpw[((size_t)k * NPROJ + c) * DI_ + k0 + k4]);
        Ws[k4 + 0][c] = v.x; Ws[k4 + 1][c] = v.y;
        Ws[k4 + 2][c] = v.z; Ws[k4 + 3][c] = v.w;
      }
    }
    __syncthreads();
#pragma unroll
    for (int kk = 0; kk < XBK; ++kk) {
      float a0 = As[tm * 2 + 0][kk], a1 = As[tm * 2 + 1][kk];
      float w0 = Ws[kk][tn * 3 + 0], w1 = Ws[kk][tn * 3 + 1], w2 = Ws[kk][tn * 3 + 2];
      acc[0][0] += a0 * w0; acc[0][1] += a0 * w1; acc[0][2] += a0 * w2;
      acc[1][0] += a1 * w0; acc[1][1] += a1 * w1; acc[1][2] += a1 * w2;
    }
    __syncthreads();
  }
#pragma unroll
  for (int i = 0; i < 2; ++i) {
    int row = row0 + tm * 2 + i;
#pragma unroll
    for (int j = 0; j < 3; ++j) {
      int cc = tn * 3 + j;
      float v = acc[i][j];
      if (cc < RK_) dts[(size_t)row * RK_ + cc] = v;
      else if (cc < RK_ + NS_) Bsb[(size_t)row * NS_ + (cc - RK_)] = v;
      else if (cc < NPROJ) Csb[(size_t)row * NS_ + (cc - RK_ - NS_)] = v;
    }
  }
}

// ---------------------------------------------------------------------------
// K5a: chunked scan pass 1.  u gathered via src_row; B/dts rows LDS-staged.
// grid = B*K*C_ = 1728, 192 thr.
// ---------------------------------------------------------------------------
__global__ void __launch_bounds__(192) k_scan1(
    const float* __restrict__ dts, const float* __restrict__ dtw,
    const float* __restrict__ dtb, const float* __restrict__ xc,
    const float* __restrict__ yc, const float* __restrict__ Bsb,
    const float* __restrict__ A_logs,
    float* __restrict__ Sdl, float* __restrict__ SHin) {
  __shared__ float sB[LC_ * NS_];    // 256
  __shared__ float sdt[LC_ * RK_];   // 96
  int blk = blockIdx.x;            // bk*C_ + c
  int bk = blk / C_, c = blk % C_;
  int b = bk / K_, k = bk % K_;
  int d = threadIdx.x;
  const float* usrc = ((k == 0 || k == 3) ? xc : yc) + (size_t)b * L_ * DI_;
  int pos0 = c * LC_;
  size_t base = (size_t)bk * L_ + pos0;
  for (int i = d; i < LC_ * NS_; i += 192) sB[i] = Bsb[base * NS_ + i];
  for (int i = d; i < LC_ * RK_; i += 192) sdt[i] = dts[base * RK_ + i];
  float A[NS_];
#pragma unroll
  for (int n = 0; n < NS_; ++n) A[n] = -__expf(A_logs[((size_t)k * DI_ + d) * NS_ + n]);
  float wdt[RK_];
#pragma unroll
  for (int r = 0; r < RK_; ++r) wdt[r] = dtw[((size_t)k * DI_ + d) * RK_ + r];
  float bias = dtb[k * DI_ + d];
  float S[NS_];
#pragma unroll
  for (int n = 0; n < NS_; ++n) S[n] = 0.f;
  float sum_dl = 0.f;
  __syncthreads();
  for (int l = 0; l < LC_; ++l) {
    float dl = delta_of(&sdt[l * RK_], wdt, bias);
    float u = usrc[(size_t)src_row(k, pos0 + l) * DI_ + d];
    float du = dl * u;
    sum_dl += dl;
    const float* Bp = &sB[l * NS_];
#pragma unroll
    for (int n = 0; n < NS_; ++n) {
      float e = __expf(dl * A[n]);
      S[n] = e * S[n] + du * Bp[n];
    }
  }
  Sdl[(size_t)blk * DI_ + d] = sum_dl;
  size_t ob = (size_t)blk * NS_ * DI_ + d;
#pragma unroll
  for (int n = 0; n < NS_; ++n) SHin[ob + (size_t)n * DI_] = S[n];
}

// ---------------------------------------------------------------------------
// K5b: chunk-level scan, parallel over (bk, n).  grid = B*K*NS = 192.
// ---------------------------------------------------------------------------
__global__ void __launch_bounds__(192) k_scan2(
    const float* __restrict__ Sdl, const float* __restrict__ A_logs,
    float* __restrict__ SHin) {
  int bkn = blockIdx.x;            // bk*NS + n
  int bk = bkn / NS_, n = bkn % NS_;
  int k = bk % K_;
  int d = threadIdx.x;
  float A = -__expf(A_logs[((size_t)k * DI_ + d) * NS_ + n]);
  float h = 0.f;
  for (int c = 0; c < C_; ++c) {
    size_t i = ((size_t)(bk * C_ + c) * NS_ + n) * DI_ + d;
    float s = SHin[i];
    float p = __expf(A * Sdl[(size_t)(bk * C_ + c) * DI_ + d]);
    SHin[i] = h;
    h = p * h + s;
  }
}

// ---------------------------------------------------------------------------
// K5c: chunked scan pass 3.  u via src_row; B/C/dts LDS-staged.
// grid = 1728, 192 thr.
// ---------------------------------------------------------------------------
__global__ void __launch_bounds__(192) k_scan3(
    const float* __restrict__ dts, const float* __restrict__ dtw,
    const float* __restrict__ dtb, const float* __restrict__ xc,
    const float* __restrict__ yc, const float* __restrict__ Bsb,
    const float* __restrict__ Csb, const float* __restrict__ A_logs,
    const float* __restrict__ Ds, const float* __restrict__ SHin,
    float* __restrict__ out_y) {
  __shared__ float sB[LC_ * NS_];
  __shared__ float sC[LC_ * NS_];
  __shared__ float sdt[LC_ * RK_];
  int blk = blockIdx.x;            // bk*C_ + c
  int bk = blk / C_, c = blk % C_;
  int b = bk / K_, k = bk % K_;
  int d = threadIdx.x;
  const float* usrc = ((k == 0 || k == 3) ? xc : yc) + (size_t)b * L_ * DI_;
  int pos0 = c * LC_;
  size_t base = (size_t)bk * L_ + pos0;
  for (int i = d; i < LC_ * NS_; i += 192) {
    sB[i] = Bsb[base * NS_ + i];
    sC[i] = Csb[base * NS_ + i];
  }
  for (int i = d; i < LC_ * RK_; i += 192) sdt[i] = dts[base * RK_ + i];
  float A[NS_];
#pragma unroll
  for (int n = 0; n < NS_; ++n) A[n] = -__expf(A_logs[((size_t)k * DI_ + d) * NS_ + n]);
  float wdt[RK_];
#pragma unroll
  for (int r = 0; r < RK_; ++r) wdt[r] = dtw[((size_t)k * DI_ + d) * RK_ + r];
  float bias = dtb[k * DI_ + d];
  float Dk = Ds[k * DI_ + d];
  float h[NS_];
  size_t hb = (size_t)blk * NS_ * DI_ + d;
#pragma unroll
  for (int n = 0; n < NS_; ++n) h[n] = SHin[hb + (size_t)n * DI_];
  __syncthreads();
  for (int l = 0; l < LC_; ++l) {
    float dl = delta_of(&sdt[l * RK_], wdt, bias);
    float u = usrc[(size_t)src_row(k, pos0 + l) * DI_ + d];
    float du = dl * u;
    const float* Bp = &sB[l * NS_];
    const float* Cp = &sC[l * NS_];
    float yacc = 0.f;
#pragma unroll
    for (int n = 0; n < NS_; ++n) {
      h[n] = __expf(dl * A[n]) * h[n] + du * Bp[n];
      yacc += h[n] * Cp[n];
    }
    out_y[(base + l) * DI_ + d] = yacc + Dk * u;
  }
}

// ---------------------------------------------------------------------------
// K6: merge + LN + gate -> LDS, out-proj GEMM from LDS; weights staged
// transposed straight from out_proj_w.  MT=32, grid 432, block 256.
// ---------------------------------------------------------------------------
constexpr int MT = 32, GS_ = 196;
__global__ void __launch_bounds__(256) k_head2(
    const float* __restrict__ out_y, const float* __restrict__ zg,
    const float* __restrict__ lnw, const float* __restrict__ lnb,
    const float* __restrict__ opw, float* __restrict__ out) {
  __shared__ float Gs[MT][GS_];
  __shared__ float Ws[32][DM_ + 1];
  int tid = threadIdx.x;
  constexpr int BPS = (B_ * L_) / MT;  // 144
  int m = blockIdx.x / BPS;
  int r0 = (blockIdx.x % BPS) * MT;

  {  // phase 1: 8 threads/row
    int row = tid >> 3, t8 = tid & 7;
    int bl = r0 + row;
    int b = bl / L_, lp = bl % L_;
    int h = lp / W_, w = lp % W_;
    int l0;
    if (m == 0) l0 = lp;
    else if (m == 1) l0 = w * H_ + h;
    else l0 = ((w - h + W_) % W_) * H_ + h;
    size_t basef = ((size_t)b * K_ + m) * L_;
    size_t baser = ((size_t)b * K_ + m + 3) * L_;
    const float* pf = out_y + (basef + l0) * DI_;
    const float* pr = out_y + (baser + (size_t)(L_ - 1 - l0)) * DI_;
    float s = 0.f, s2 = 0.f;
#pragma unroll
    for (int j = 0; j < 6; ++j) {
      int c4 = t8 * 24 + j * 4;
      float4 a = *reinterpret_cast<const float4*>(&pf[c4]);
      float4 bb = *reinterpret_cast<const float4*>(&pr[c4]);
      float4 t;
      t.x = a.x + bb.x; t.y = a.y + bb.y; t.z = a.z + bb.z; t.w = a.w + bb.w;
      s += t.x + t.y + t.z + t.w;
      s2 += t.x * t.x + t.y * t.y + t.z * t.z + t.w * t.w;
      *reinterpret_cast<float4*>(&Gs[row][c4]) = t;
    }
    s += __shfl_xor(s, 1, 64);  s2 += __shfl_xor(s2, 1, 64);
    s += __shfl_xor(s, 2, 64);  s2 += __shfl_xor(s2, 2, 64);
    s += __shfl_xor(s, 4, 64);  s2 += __shfl_xor(s2, 4, 64);
    float mu = s * (1.f / DI_);
    float var = fmaxf(s2 * (1.f / DI_) - mu * mu, 0.f);
    float rs = rsqrtf(var + 1e-5f);
    const float* zp = zg + (size_t)bl * DI_;
#pragma unroll
    for (int j = 0; j < 6; ++j) {
      int c4 = t8 * 24 + j * 4;
      float4 t = *reinterpret_cast<const float4*>(&Gs[row][c4]);
      float4 zv = *reinterpret_cast<const float4*>(&zp[c4]);
      t.x = ((t.x - mu) * rs * lnw[c4 + 0] + lnb[c4 + 0]) * zv.x;
      t.y = ((t.y - mu) * rs * lnw[c4 + 1] + lnb[c4 + 1]) * zv.y;
      t.z = ((t.z - mu) * rs * lnw[c4 + 2] + lnb[c4 + 2]) * zv.z;
      t.w = ((t.w - mu) * rs * lnw[c4 + 3] + lnb[c4 + 3]) * zv.w;
      *reinterpret_cast<float4*>(&Gs[row][c4]) = t;
    }
  }
  __syncthreads();

  int tm = tid >> 4, tn = tid & 15;
  float acc[2][6];
#pragma unroll
  for (int i = 0; i < 2; ++i)
#pragma unroll
    for (int j = 0; j < 6; ++j) acc[i][j] = 0.f;

  for (int k0 = 0; k0 < DI_; k0 += 32) {
    // Ws[kk][o] = opw[o*DI + k0+kk], float4 along kk
#pragma unroll
    for (int it = 0; it < 3; ++it) {
      int i = tid + it * 256;        // [0,768)
      int o = i >> 3, k4 = (i & 7) << 2;
      const float4 v = *reinterpret_cast<const float4*>(
          &opw[(size_t)o * DI_ + k0 + k4]);
      Ws[k4 + 0][o] = v.x; Ws[k4 + 1][o] = v.y;
      Ws[k4 + 2][o] = v.z; Ws[k4 + 3][o] = v.w;
    }
    __syncthreads();
#pragma unroll
    for (int kk = 0; kk < 32; ++kk) {
      float a0 = Gs[tm * 2 + 0][k0 + kk], a1 = Gs[tm * 2 + 1][k0 + kk];
      float w[6];
#pragma unroll
      for (int j = 0; j < 6; ++j) w[j] = Ws[kk][tn * 6 + j];
#pragma unroll
      for (int j = 0; j < 6; ++j) {
        acc[0][j] += a0 * w[j];
        acc[1][j] += a1 * w[j];
      }
    }
    __syncthreads();
  }
  size_t obase = ((size_t)m * (B_ * L_) + r0) * DM_;
#pragma unroll
  for (int i = 0; i < 2; ++i) {
    size_t ob = obase + (size_t)(tm * 2 + i) * DM_ + tn * 6;
#pragma unroll
    for (int j = 0; j < 6; ++j) out[ob + j] = acc[i][j];
  }
}

}  // namespace

extern "C" void kernel_launch(void* const* d_in, const int* in_sizes, int n_in,
                              void* d_out, int out_size, void* d_ws, size_t ws_size,
                              hipStream_t stream) {
  const float* x = (const float*)d_in[0];
  const float* y = (const float*)d_in[1];
  const float* kin = (const float*)d_in[2];
  const float* in_proj_w = (const float*)d_in[3];
  const float* conv_w = (const float*)d_in[4];
  const float* conv_b = (const float*)d_in[5];
  const float* x_proj_w = (const float*)d_in[6];
  const float* dt_w = (const float*)d_in[7];
  const float* dt_b = (const float*)d_in[8];
  const float* A_logs = (const float*)d_in[9];
  const float* Ds = (const float*)d_in[10];
  const float* ln_w = (const float*)d_in[11];
  const float* ln_b = (const float*)d_in[12];
  const float* out_proj_w = (const float*)d_in[13];
  float* out = (float*)d_out;

  float* ws = (float*)d_ws;
  const size_t BLD = (size_t)B_ * L_ * DI_;
  const size_t BKLD = (size_t)B_ * K_ * L_ * DI_;
  const size_t BKLN = (size_t)B_ * K_ * L_ * NS_;
  const size_t PSN = (size_t)B_ * K_ * C_ * NS_ * DI_;
  float* xv = ws;     ws += BLD;
  float* yv = ws;     ws += BLD;
  float* zg = ws;     ws += BLD;
  float* xc = ws;     ws += BLD;
  float* yc = ws;     ws += BLD;
  float* Bsb = ws;    ws += BKLN;
  float* Csb = ws;    ws += BKLN;
  float* out_y = ws;  ws += BKLD;
  float* SHin = ws;   ws += PSN;
  float* Sdl = ws;    ws += (size_t)B_ * K_ * C_ * DI_;
  float* dts = ws;    ws += (size_t)B_ * K_ * L_ * RK_;

  k_inproj2<<<3 * B_ * L_ / IM, 256, 0, stream>>>(x, y, kin, in_proj_w, xv, yv, zg);
  k_conv2<<<B_ * L_ / 4, 192, 0, stream>>>(xv, yv, conv_w, conv_b, xc, yc);
  k_xdbl3<<<B_ * K_ * L_ / XM, 256, 0, stream>>>(xc, yc, x_proj_w, dts, Bsb, Csb);
  k_scan1<<<B_ * K_ * C_, 192, 0, stream>>>(dts, dt_w, dt_b, xc, yc, Bsb, A_logs,
                                            Sdl, SHin);
  k_scan2<<<B_ * K_ * NS_, 192, 0, stream>>>(Sdl, A_logs, SHin);
  k_scan3<<<B_ * K_ * C_, 192, 0, stream>>>(dts, dt_w, dt_b, xc, yc, Bsb, Csb,
                                            A_logs, Ds, SHin, out_y);
  k_head2<<<3 * B_ * L_ / MT, 256, 0, stream>>>(out_y, zg, ln_w, ln_b, out_proj_w, out);
}

// Round 13
// 159.211 us; speedup vs baseline: 9.8133x; 1.0134x over previous
//
#include <hip/hip_runtime.h>
#include <hip/hip_bf16.h>

namespace {

constexpr int B_ = 2, H_ = 48, W_ = 48, DM_ = 96, DI_ = 192, NS_ = 16, RK_ = 6, K_ = 6;
constexpr int L_ = H_ * W_;
constexpr int C_ = 144;           // chunks per (b,k) stream
constexpr int LC_ = L_ / C_;      // 16 steps per chunk
constexpr int NPROJ = RK_ + 2 * NS_;  // 38
constexpr int NPAD = 48;

__device__ __forceinline__ float sigmoidf_(float x) { return 1.f / (1.f + __expf(-x)); }

// softplus(dtb + dts(row)·dtw(d)) — evaluated identically in fused-scan1 and scan3.
__device__ __forceinline__ float delta_of(const float* __restrict__ dp,
                                          const float* __restrict__ wdt,
                                          float bias) {
  float s = bias;
#pragma unroll
  for (int r = 0; r < RK_; ++r) s += dp[r] * wdt[r];
  return (s > 20.f) ? s : __logf(1.f + __expf(s));
}

// Row of xc/yc (pixel-major l = h*W+w) holding direction-k stream position pos.
__device__ __forceinline__ int src_row(int k, int pos) {
  int pk = (k >= 3) ? (L_ - 1 - pos) : pos;
  int kk = (k >= 3) ? k - 3 : k;
  if (kk == 0) return pk;
  int h = pk % H_, wcol = pk / H_;        // pk = wcol*H + h
  if (kk == 1) return h * W_ + wcol;
  return h * W_ + (wcol + h) % W_;        // diag: orig col = (wcol+h)%W
}

// ---------------------------------------------------------------------------
// K1: in_proj tiled GEMM, weights staged transposed straight from in_proj_w.
// IM=32 -> grid 432, block 256.
// ---------------------------------------------------------------------------
constexpr int IM = 32, IBK = 32;
__global__ void __launch_bounds__(256) k_inproj2(
    const float* __restrict__ x, const float* __restrict__ y,
    const float* __restrict__ kin, const float* __restrict__ inpw,
    float* __restrict__ xv, float* __restrict__ yv, float* __restrict__ zg) {
  __shared__ float As[IM][IBK + 1];
  __shared__ float Ws[IBK][DI_ + 1];
  int tid = threadIdx.x;
  constexpr int BPS = (B_ * L_) / IM;   // 144 blocks per stream
  int s = blockIdx.x / BPS;
  int row0 = (blockIdx.x % BPS) * IM;
  const float* src = (s == 0) ? x : (s == 1) ? y : kin;
  float* dst = (s == 0) ? xv : (s == 1) ? yv : zg;
  int nbase = (s == 2) ? DI_ : 0;
  int tm = tid >> 4, tn = tid & 15;     // 16 x 16
  float acc[2][12];
#pragma unroll
  for (int i = 0; i < 2; ++i)
#pragma unroll
    for (int j = 0; j < 12; ++j) acc[i][j] = 0.f;

  for (int k0 = 0; k0 < DM_; k0 += IBK) {
    {  // A tile: 32x32 = 256 float4, 1/thread
      int r = tid >> 3, c4 = (tid & 7) << 2;
      const float4 v = *reinterpret_cast<const float4*>(
          &src[(size_t)(row0 + r) * DM_ + k0 + c4]);
      As[r][c4] = v.x; As[r][c4 + 1] = v.y; As[r][c4 + 2] = v.z; As[r][c4 + 3] = v.w;
    }
    // W tile transposed on the fly: Ws[kk][col] = inpw[(nbase+col)*DM + k0+kk]
#pragma unroll
    for (int it = 0; it < 6; ++it) {
      int i = tid + it * 256;        // [0,1536)
      int col = i >> 3, k4 = (i & 7) << 2;
      const float4 v = *reinterpret_cast<const float4*>(
          &inpw[(size_t)(nbase + col) * DM_ + k0 + k4]);
      Ws[k4 + 0][col] = v.x; Ws[k4 + 1][col] = v.y;
      Ws[k4 + 2][col] = v.z; Ws[k4 + 3][col] = v.w;
    }
    __syncthreads();
#pragma unroll
    for (int kk = 0; kk < IBK; ++kk) {
      float a0 = As[tm * 2 + 0][kk], a1 = As[tm * 2 + 1][kk];
      float w[12];
#pragma unroll
      for (int j = 0; j < 12; ++j) w[j] = Ws[kk][tn * 12 + j];
#pragma unroll
      for (int j = 0; j < 12; ++j) {
        acc[0][j] += a0 * w[j];
        acc[1][j] += a1 * w[j];
      }
    }
    __syncthreads();
  }
#pragma unroll
  for (int i = 0; i < 2; ++i) {
    size_t ob = (size_t)(row0 + tm * 2 + i) * DI_ + tn * 12;
#pragma unroll
    for (int j4 = 0; j4 < 3; ++j4) {
      float4 v;
      v.x = acc[i][j4 * 4 + 0]; v.y = acc[i][j4 * 4 + 1];
      v.z = acc[i][j4 * 4 + 2]; v.w = acc[i][j4 * 4 + 3];
      if (s == 2) {
        v.x *= sigmoidf_(v.x); v.y *= sigmoidf_(v.y);
        v.z *= sigmoidf_(v.z); v.w *= sigmoidf_(v.w);
      }
      *reinterpret_cast<float4*>(&dst[ob + j4 * 4]) = v;
    }
  }
}

// ---------------------------------------------------------------------------
// K2: conv 3x3 + SiLU -> xc, yc in pixel-major (b,l,d).  2 stores/thread.
// grid = B*L/4 = 1152, 192 threads.
// ---------------------------------------------------------------------------
__global__ void __launch_bounds__(192) k_conv2(
    const float* __restrict__ xv, const float* __restrict__ yv,
    const float* __restrict__ cw, const float* __restrict__ cb,
    float* __restrict__ xc, float* __restrict__ yc) {
  __shared__ float scw[9 * DI_];
  int tid = threadIdx.x;
  for (int i = tid; i < 9 * DI_; i += 192) {
    int d = i / 9, j = i % 9;
    scw[j * DI_ + d] = cw[i];
  }
  __syncthreads();
  int p = tid / 48, q = tid % 48;
  int gl = blockIdx.x * 4 + p;
  int b = gl / L_, l = gl % L_;
  int h = l / W_, w = l % W_;
  int d4 = q << 2;
  float4 ax = *reinterpret_cast<const float4*>(&cb[d4]);
  float4 ay = ax;
#pragma unroll
  for (int kh = 0; kh < 3; ++kh) {
    int hh = h + kh - 1;
    if ((unsigned)hh >= (unsigned)H_) continue;
#pragma unroll
    for (int kw = 0; kw < 3; ++kw) {
      int ww = w + kw - 1;
      if ((unsigned)ww >= (unsigned)W_) continue;
      float4 wk = *reinterpret_cast<const float4*>(&scw[(kh * 3 + kw) * DI_ + d4]);
      size_t idx = ((size_t)b * L_ + hh * W_ + ww) * DI_ + d4;
      float4 vx = *reinterpret_cast<const float4*>(&xv[idx]);
      float4 vy = *reinterpret_cast<const float4*>(&yv[idx]);
      ax.x += vx.x * wk.x; ax.y += vx.y * wk.y; ax.z += vx.z * wk.z; ax.w += vx.w * wk.w;
      ay.x += vy.x * wk.x; ay.y += vy.y * wk.y; ay.z += vy.z * wk.z; ay.w += vy.w * wk.w;
    }
  }
  ax.x *= sigmoidf_(ax.x); ax.y *= sigmoidf_(ax.y);
  ax.z *= sigmoidf_(ax.z); ax.w *= sigmoidf_(ax.w);
  ay.x *= sigmoidf_(ay.x); ay.y *= sigmoidf_(ay.y);
  ay.z *= sigmoidf_(ay.z); ay.w *= sigmoidf_(ay.w);
  size_t ob = (size_t)gl * DI_ + d4;
  *reinterpret_cast<float4*>(&xc[ob]) = ax;
  *reinterpret_cast<float4*>(&yc[ob]) = ay;
}

// ---------------------------------------------------------------------------
// K3 fused: x_dbl GEMM + scan pass 1 for the block's 2 chunks.
// Block = 32 rows (2 chunks of LC=16) within one k.  grid 864, block 256.
// The GEMM's A-tile (u) and result tile (dts/Bs) stay in LDS for the scan.
// ---------------------------------------------------------------------------
constexpr int XM = 32, XBK = 32, XAS = 196;
__global__ void __launch_bounds__(256) k_xdbl_scan1(
    const float* __restrict__ xc, const float* __restrict__ yc,
    const float* __restrict__ xpw, const float* __restrict__ dtw,
    const float* __restrict__ dtb, const float* __restrict__ A_logs,
    float* __restrict__ dts, float* __restrict__ Bsb, float* __restrict__ Csb,
    float* __restrict__ Sdl, float* __restrict__ SHin) {
  __shared__ float As[XM][XAS];      // full u tile 32 x 192 (stride 196)
  __shared__ float Ws[XBK][NPAD];
  __shared__ float xd[XM][NPAD + 1]; // x_dbl result tile
  int tid = threadIdx.x;
  int row0 = blockIdx.x * XM;
  int b = row0 / (K_ * L_);
  int k = (row0 / L_) % K_;
  int pos0 = row0 % L_;
  const float* usrc = ((k == 0 || k == 3) ? xc : yc) + (size_t)b * L_ * DI_;
  int tm = tid >> 4, tn = tid & 15;

  // stage full A tile once: 32 rows x 192 = 1536 float4, 6/thread
#pragma unroll
  for (int it = 0; it < 6; ++it) {
    int i = tid + it * 256;
    int r = i / 48, c4 = (i % 48) << 2;
    int srow = src_row(k, pos0 + r);
    const float4 v = *reinterpret_cast<const float4*>(
        &usrc[(size_t)srow * DI_ + c4]);
    As[r][c4] = v.x; As[r][c4 + 1] = v.y; As[r][c4 + 2] = v.z; As[r][c4 + 3] = v.w;
  }
  // zero the pad columns of Ws once
  for (int i = tid; i < XBK * (NPAD - NPROJ); i += 256) {
    int kk = i / (NPAD - NPROJ), c = NPROJ + i % (NPAD - NPROJ);
    Ws[kk][c] = 0.f;
  }
  float acc[2][3];
#pragma unroll
  for (int i = 0; i < 2; ++i)
#pragma unroll
    for (int j = 0; j < 3; ++j) acc[i][j] = 0.f;

  for (int k0 = 0; k0 < DI_; k0 += XBK) {
    // Ws[kk][c] = xpw[(k*38+c)*DI + k0+kk], float4 along kk
#pragma unroll
    for (int it = 0; it < 2; ++it) {
      int i = tid + it * 256;
      if (i < NPROJ * 8) {
        int c = i >> 3, k4 = (i & 7) << 2;
        const float4 v = *reinterpret_cast<const float4*>(
            &xpw[((size_t)k * NPROJ + c) * DI_ + k0 + k4]);
        Ws[k4 + 0][c] = v.x; Ws[k4 + 1][c] = v.y;
        Ws[k4 + 2][c] = v.z; Ws[k4 + 3][c] = v.w;
      }
    }
    __syncthreads();
#pragma unroll
    for (int kk = 0; kk < XBK; ++kk) {
      float a0 = As[tm * 2 + 0][k0 + kk], a1 = As[tm * 2 + 1][k0 + kk];
      float w0 = Ws[kk][tn * 3 + 0], w1 = Ws[kk][tn * 3 + 1], w2 = Ws[kk][tn * 3 + 2];
      acc[0][0] += a0 * w0; acc[0][1] += a0 * w1; acc[0][2] += a0 * w2;
      acc[1][0] += a1 * w0; acc[1][1] += a1 * w1; acc[1][2] += a1 * w2;
    }
    __syncthreads();
  }
  // spill result tile to LDS + global (Bs/Cs/dts needed by scan3)
#pragma unroll
  for (int i = 0; i < 2; ++i) {
    int r = tm * 2 + i;
    int row = row0 + r;
#pragma unroll
    for (int j = 0; j < 3; ++j) {
      int cc = tn * 3 + j;
      float v = acc[i][j];
      xd[r][cc] = v;
      if (cc < RK_) dts[(size_t)row * RK_ + cc] = v;
      else if (cc < RK_ + NS_) Bsb[(size_t)row * NS_ + (cc - RK_)] = v;
      else if (cc < NPROJ) Csb[(size_t)row * NS_ + (cc - RK_ - NS_)] = v;
    }
  }
  __syncthreads();

  // ---- phase 2: scan1 for the 2 chunks, u/B/dts all from LDS ----
  if (tid < DI_) {
    int d = tid;
    float A[NS_];
#pragma unroll
    for (int n = 0; n < NS_; ++n)
      A[n] = -__expf(A_logs[((size_t)k * DI_ + d) * NS_ + n]);
    float wdt[RK_];
#pragma unroll
    for (int r = 0; r < RK_; ++r) wdt[r] = dtw[((size_t)k * DI_ + d) * RK_ + r];
    float bias = dtb[k * DI_ + d];
#pragma unroll
    for (int ch = 0; ch < 2; ++ch) {
      float S[NS_];
#pragma unroll
      for (int n = 0; n < NS_; ++n) S[n] = 0.f;
      float sum_dl = 0.f;
      for (int l = 0; l < LC_; ++l) {
        int r = ch * LC_ + l;
        float dl = delta_of(&xd[r][0], wdt, bias);
        float u = As[r][d];
        float du = dl * u;
        sum_dl += dl;
        const float* Bp = &xd[r][RK_];
#pragma unroll
        for (int n = 0; n < NS_; ++n) {
          float e = __expf(dl * A[n]);
          S[n] = e * S[n] + du * Bp[n];
        }
      }
      int gchunk = blockIdx.x * 2 + ch;
      Sdl[(size_t)gchunk * DI_ + d] = sum_dl;
      size_t ob = (size_t)gchunk * NS_ * DI_ + d;
#pragma unroll
      for (int n = 0; n < NS_; ++n) SHin[ob + (size_t)n * DI_] = S[n];
    }
  }
}

// ---------------------------------------------------------------------------
// K5b: chunk-level scan, parallel over (bk, n).  grid = B*K*NS = 192.
// ---------------------------------------------------------------------------
__global__ void __launch_bounds__(192) k_scan2(
    const float* __restrict__ Sdl, const float* __restrict__ A_logs,
    float* __restrict__ SHin) {
  int bkn = blockIdx.x;            // bk*NS + n
  int bk = bkn / NS_, n = bkn % NS_;
  int k = bk % K_;
  int d = threadIdx.x;
  float A = -__expf(A_logs[((size_t)k * DI_ + d) * NS_ + n]);
  float h = 0.f;
  for (int c = 0; c < C_; ++c) {
    size_t i = ((size_t)(bk * C_ + c) * NS_ + n) * DI_ + d;
    float s = SHin[i];
    float p = __expf(A * Sdl[(size_t)(bk * C_ + c) * DI_ + d]);
    SHin[i] = h;
    h = p * h + s;
  }
}

// ---------------------------------------------------------------------------
// K5c: chunked scan pass 3.  u via src_row; B/C/dts LDS-staged.
// grid = 1728, 192 thr.
// ---------------------------------------------------------------------------
__global__ void __launch_bounds__(192) k_scan3(
    const float* __restrict__ dts, const float* __restrict__ dtw,
    const float* __restrict__ dtb, const float* __restrict__ xc,
    const float* __restrict__ yc, const float* __restrict__ Bsb,
    const float* __restrict__ Csb, const float* __restrict__ A_logs,
    const float* __restrict__ Ds, const float* __restrict__ SHin,
    float* __restrict__ out_y) {
  __shared__ float sB[LC_ * NS_];
  __shared__ float sC[LC_ * NS_];
  __shared__ float sdt[LC_ * RK_];
  int blk = blockIdx.x;            // bk*C_ + c
  int bk = blk / C_, c = blk % C_;
  int b = bk / K_, k = bk % K_;
  int d = threadIdx.x;
  const float* usrc = ((k == 0 || k == 3) ? xc : yc) + (size_t)b * L_ * DI_;
  int pos0 = c * LC_;
  size_t base = (size_t)bk * L_ + pos0;
  for (int i = d; i < LC_ * NS_; i += 192) {
    sB[i] = Bsb[base * NS_ + i];
    sC[i] = Csb[base * NS_ + i];
  }
  for (int i = d; i < LC_ * RK_; i += 192) sdt[i] = dts[base * RK_ + i];
  float A[NS_];
#pragma unroll
  for (int n = 0; n < NS_; ++n) A[n] = -__expf(A_logs[((size_t)k * DI_ + d) * NS_ + n]);
  float wdt[RK_];
#pragma unroll
  for (int r = 0; r < RK_; ++r) wdt[r] = dtw[((size_t)k * DI_ + d) * RK_ + r];
  float bias = dtb[k * DI_ + d];
  float Dk = Ds[k * DI_ + d];
  float h[NS_];
  size_t hb = (size_t)blk * NS_ * DI_ + d;
#pragma unroll
  for (int n = 0; n < NS_; ++n) h[n] = SHin[hb + (size_t)n * DI_];
  __syncthreads();
  for (int l = 0; l < LC_; ++l) {
    float dl = delta_of(&sdt[l * RK_], wdt, bias);
    float u = usrc[(size_t)src_row(k, pos0 + l) * DI_ + d];
    float du = dl * u;
    const float* Bp = &sB[l * NS_];
    const float* Cp = &sC[l * NS_];
    float yacc = 0.f;
#pragma unroll
    for (int n = 0; n < NS_; ++n) {
      h[n] = __expf(dl * A[n]) * h[n] + du * Bp[n];
      yacc += h[n] * Cp[n];
    }
    out_y[(base + l) * DI_ + d] = yacc + Dk * u;
  }
}

// ---------------------------------------------------------------------------
// K6: merge + LN + gate -> LDS, out-proj GEMM from LDS; weights staged
// transposed straight from out_proj_w.  MT=32, grid 432, block 256.
// ---------------------------------------------------------------------------
constexpr int MT = 32, GS_ = 196;
__global__ void __launch_bounds__(256) k_head2(
    const float* __restrict__ out_y, const float* __restrict__ zg,
    const float* __restrict__ lnw, const float* __restrict__ lnb,
    const float* __restrict__ opw, float* __restrict__ out) {
  __shared__ float Gs[MT][GS_];
  __shared__ float Ws[32][DM_ + 1];
  int tid = threadIdx.x;
  constexpr int BPS = (B_ * L_) / MT;  // 144
  int m = blockIdx.x / BPS;
  int r0 = (blockIdx.x % BPS) * MT;

  {  // phase 1: 8 threads/row
    int row = tid >> 3, t8 = tid & 7;
    int bl = r0 + row;
    int b = bl / L_, lp = bl % L_;
    int h = lp / W_, w = lp % W_;
    int l0;
    if (m == 0) l0 = lp;
    else if (m == 1) l0 = w * H_ + h;
    else l0 = ((w - h + W_) % W_) * H_ + h;
    size_t basef = ((size_t)b * K_ + m) * L_;
    size_t baser = ((size_t)b * K_ + m + 3) * L_;
    const float* pf = out_y + (basef + l0) * DI_;
    const float* pr = out_y + (baser + (size_t)(L_ - 1 - l0)) * DI_;
    float s = 0.f, s2 = 0.f;
#pragma unroll
    for (int j = 0; j < 6; ++j) {
      int c4 = t8 * 24 + j * 4;
      float4 a = *reinterpret_cast<const float4*>(&pf[c4]);
      float4 bb = *reinterpret_cast<const float4*>(&pr[c4]);
      float4 t;
      t.x = a.x + bb.x; t.y = a.y + bb.y; t.z = a.z + bb.z; t.w = a.w + bb.w;
      s += t.x + t.y + t.z + t.w;
      s2 += t.x * t.x + t.y * t.y + t.z * t.z + t.w * t.w;
      *reinterpret_cast<float4*>(&Gs[row][c4]) = t;
    }
    s += __shfl_xor(s, 1, 64);  s2 += __shfl_xor(s2, 1, 64);
    s += __shfl_xor(s, 2, 64);  s2 += __shfl_xor(s2, 2, 64);
    s += __shfl_xor(s, 4, 64);  s2 += __shfl_xor(s2, 4, 64);
    float mu = s * (1.f / DI_);
    float var = fmaxf(s2 * (1.f / DI_) - mu * mu, 0.f);
    float rs = rsqrtf(var + 1e-5f);
    const float* zp = zg + (size_t)bl * DI_;
#pragma unroll
    for (int j = 0; j < 6; ++j) {
      int c4 = t8 * 24 + j * 4;
      float4 t = *reinterpret_cast<const float4*>(&Gs[row][c4]);
      float4 zv = *reinterpret_cast<const float4*>(&zp[c4]);
      t.x = ((t.x - mu) * rs * lnw[c4 + 0] + lnb[c4 + 0]) * zv.x;
      t.y = ((t.y - mu) * rs * lnw[c4 + 1] + lnb[c4 + 1]) * zv.y;
      t.z = ((t.z - mu) * rs * lnw[c4 + 2] + lnb[c4 + 2]) * zv.z;
      t.w = ((t.w - mu) * rs * lnw[c4 + 3] + lnb[c4 + 3]) * zv.w;
      *reinterpret_cast<float4*>(&Gs[row][c4]) = t;
    }
  }
  __syncthreads();

  int tm = tid >> 4, tn = tid & 15;
  float acc[2][6];
#pragma unroll
  for (int i = 0; i < 2; ++i)
#pragma unroll
    for (int j = 0; j < 6; ++j) acc[i][j] = 0.f;

  for (int k0 = 0; k0 < DI_; k0 += 32) {
    // Ws[kk][o] = opw[o*DI + k0+kk], float4 along kk
#pragma unroll
    for (int it = 0; it < 3; ++it) {
      int i = tid + it * 256;        // [0,768)
      int o = i >> 3, k4 = (i & 7) << 2;
      const float4 v = *reinterpret_cast<const float4*>(
          &opw[(size_t)o * DI_ + k0 + k4]);
      Ws[k4 + 0][o] = v.x; Ws[k4 + 1][o] = v.y;
      Ws[k4 + 2][o] = v.z; Ws[k4 + 3][o] = v.w;
    }
    __syncthreads();
#pragma unroll
    for (int kk = 0; kk < 32; ++kk) {
      float a0 = Gs[tm * 2 + 0][k0 + kk], a1 = Gs[tm * 2 + 1][k0 + kk];
      float w[6];
#pragma unroll
      for (int j = 0; j < 6; ++j) w[j] = Ws[kk][tn * 6 + j];
#pragma unroll
      for (int j = 0; j < 6; ++j) {
        acc[0][j] += a0 * w[j];
        acc[1][j] += a1 * w[j];
      }
    }
    __syncthreads();
  }
  size_t obase = ((size_t)m * (B_ * L_) + r0) * DM_;
#pragma unroll
  for (int i = 0; i < 2; ++i) {
    size_t ob = obase + (size_t)(tm * 2 + i) * DM_ + tn * 6;
#pragma unroll
    for (int j = 0; j < 6; ++j) out[ob + j] = acc[i][j];
  }
}

}  // namespace

extern "C" void kernel_launch(void* const* d_in, const int* in_sizes, int n_in,
                              void* d_out, int out_size, void* d_ws, size_t ws_size,
                              hipStream_t stream) {
  const float* x = (const float*)d_in[0];
  const float* y = (const float*)d_in[1];
  const float* kin = (const float*)d_in[2];
  const float* in_proj_w = (const float*)d_in[3];
  const float* conv_w = (const float*)d_in[4];
  const float* conv_b = (const float*)d_in[5];
  const float* x_proj_w = (const float*)d_in[6];
  const float* dt_w = (const float*)d_in[7];
  const float* dt_b = (const float*)d_in[8];
  const float* A_logs = (const float*)d_in[9];
  const float* Ds = (const float*)d_in[10];
  const float* ln_w = (const float*)d_in[11];
  const float* ln_b = (const float*)d_in[12];
  const float* out_proj_w = (const float*)d_in[13];
  float* out = (float*)d_out;

  float* ws = (float*)d_ws;
  const size_t BLD = (size_t)B_ * L_ * DI_;
  const size_t BKLD = (size_t)B_ * K_ * L_ * DI_;
  const size_t BKLN = (size_t)B_ * K_ * L_ * NS_;
  const size_t PSN = (size_t)B_ * K_ * C_ * NS_ * DI_;
  float* xv = ws;     ws += BLD;
  float* yv = ws;     ws += BLD;
  float* zg = ws;     ws += BLD;
  float* xc = ws;     ws += BLD;
  float* yc = ws;     ws += BLD;
  float* Bsb = ws;    ws += BKLN;
  float* Csb = ws;    ws += BKLN;
  float* out_y = ws;  ws += BKLD;
  float* SHin = ws;   ws += PSN;
  float* Sdl = ws;    ws += (size_t)B_ * K_ * C_ * DI_;
  float* dts = ws;    ws += (size_t)B_ * K_ * L_ * RK_;

  k_inproj2<<<3 * B_ * L_ / IM, 256, 0, stream>>>(x, y, kin, in_proj_w, xv, yv, zg);
  k_conv2<<<B_ * L_ / 4, 192, 0, stream>>>(xv, yv, conv_w, conv_b, xc, yc);
  k_xdbl_scan1<<<B_ * K_ * L_ / XM, 256, 0, stream>>>(xc, yc, x_proj_w, dt_w, dt_b,
                                                      A_logs, dts, Bsb, Csb, Sdl, SHin);
  k_scan2<<<B_ * K_ * NS_, 192, 0, stream>>>(Sdl, A_logs, SHin);
  k_scan3<<<B_ * K_ * C_, 192, 0, stream>>>(dts, dt_w, dt_b, xc, yc, Bsb, Csb,
                                            A_logs, Ds, SHin, out_y);
  k_head2<<<3 * B_ * L_ / MT, 256, 0, stream>>>(out_y, zg, ln_w, ln_b, out_proj_w, out);
}